// Round 2
// baseline (1067.166 us; speedup 1.0000x reference)
//
#include <hip/hip_runtime.h>
#include <stdint.h>

#define NBATCH 64
#define HH 512
#define WW 512
#define NPIX 262144            // 512*512
#define BINS1 2048             // key bits [31:21]
#define BINS2 2048             // key bits [20:10]
#define BINS3 1024             // key bits [9:0]
#define TRIM_IDX 209715u       // int((1-0.2)*262144)
#define HGX 16                 // hist blocks per batch
#define HITER (NPIX/4/HGX/256) // float4 iters per hist block

// ---------------- workspace layout (u32 units) ----------------
#define SZ_C1 (2*NBATCH*BINS1)
#define OFF_C1 0
#define OFF_S1 (OFF_C1 + SZ_C1)
#define OFF_C2 (OFF_S1 + SZ_C1)
#define OFF_S2 (OFF_C2 + SZ_C1)
#define OFF_C3 (OFF_S2 + SZ_C1)
#define SZ_C3 (2*NBATCH*BINS3)
#define OFF_S3 (OFF_C3 + SZ_C3)
#define OFF_STATE (OFF_S3 + SZ_C3)
// state (survives the mid-pipeline hist re-zero):
#define ST_N     (OFF_STATE)        // u32 [128]  masked count per (tensor,batch)
#define ST_N2    (ST_N + 128)       // u32 [128]  count of x > median (mask for trim/grad)
#define ST_B1    (ST_N2 + 128)      // u32 [128]
#define ST_B2    (ST_B1 + 128)      // u32 [128]
#define ST_RANK  (ST_B2 + 128)      // u32 [128]
#define ST_CLT   (ST_RANK + 128)    // u32 [128]  count of keys strictly below bucket
#define ST_SLT   (ST_CLT + 128)     // f32 [128]  sum of values strictly below bucket
#define ST_STOT  (ST_SLT + 128)     // f32 [128]
#define ST_SHIFT (ST_STOT + 128)    // f32 [128]  median per (tensor,batch)
#define ST_SCL   (ST_SHIFT + 128)   // f32 [128]  robust scale
#define ST_TRIMA (ST_SCL + 128)     // f32 [64]   per-batch trimmed loss
#define ST_GSUM  (ST_TRIMA + 64)    // f32 [4*64] gradient sums
#define ST_GCNT  (ST_GSUM + 256)    // u32 [4*64] gradient mask counts
#define WS_TOTAL (ST_GCNT + 256)

// order-preserving float -> u32 key (total order incl. negatives)
__device__ __forceinline__ uint32_t fkey(float x) {
    uint32_t u = __float_as_uint(x);
    return (u & 0x80000000u) ? ~u : (u | 0x80000000u);
}
__device__ __forceinline__ float funkey(uint32_t k) {
    return __uint_as_float((k & 0x80000000u) ? (k & 0x7fffffffu) : ~k);
}

// ================= median histogram passes (both tensors, masked by tgt>0) ===========
__global__ __launch_bounds__(256) void k_medhist1(const float* __restrict__ pred, const float* __restrict__ tgt,
                                                  uint32_t* __restrict__ cnt, float* __restrict__ sum) {
    __shared__ uint32_t cP[BINS1], cT[BINS1];
    __shared__ float sP[BINS1], sT[BINS1];
    const int tid = threadIdx.x;
    for (int i = tid; i < BINS1; i += 256) { cP[i]=0u; cT[i]=0u; sP[i]=0.f; sT[i]=0.f; }
    __syncthreads();
    const int b = blockIdx.y;
    const float4* p4 = (const float4*)pred;
    const float4* t4 = (const float4*)tgt;
    size_t base = (size_t)b*(NPIX/4) + (size_t)blockIdx.x*(NPIX/4/HGX);
    for (int it = 0; it < HITER; ++it) {
        size_t idx = base + (size_t)it*256 + tid;
        float4 pv = p4[idx], tv = t4[idx];
        float pa[4] = {pv.x, pv.y, pv.z, pv.w};
        float ta[4] = {tv.x, tv.y, tv.z, tv.w};
#pragma unroll
        for (int j = 0; j < 4; ++j) {
            if (ta[j] > 0.f) {
                uint32_t kp = fkey(pa[j]) >> 21, kt = fkey(ta[j]) >> 21;
                atomicAdd(&cP[kp], 1u); atomicAdd(&sP[kp], pa[j]);
                atomicAdd(&cT[kt], 1u); atomicAdd(&sT[kt], ta[j]);
            }
        }
    }
    __syncthreads();
    for (int i = tid; i < BINS1; i += 256) {
        if (cP[i]) { atomicAdd(&cnt[(size_t)b*BINS1+i], cP[i]); atomicAdd(&sum[(size_t)b*BINS1+i], sP[i]); }
        if (cT[i]) { atomicAdd(&cnt[(size_t)(NBATCH+b)*BINS1+i], cT[i]); atomicAdd(&sum[(size_t)(NBATCH+b)*BINS1+i], sT[i]); }
    }
}

__global__ __launch_bounds__(256) void k_medhist2(const float* __restrict__ pred, const float* __restrict__ tgt,
                                                  const uint32_t* __restrict__ b1arr,
                                                  uint32_t* __restrict__ cnt, float* __restrict__ sum) {
    __shared__ uint32_t cP[BINS2], cT[BINS2];
    __shared__ float sP[BINS2], sT[BINS2];
    const int tid = threadIdx.x;
    for (int i = tid; i < BINS2; i += 256) { cP[i]=0u; cT[i]=0u; sP[i]=0.f; sT[i]=0.f; }
    __syncthreads();
    const int b = blockIdx.y;
    const uint32_t b1p = b1arr[b], b1t = b1arr[NBATCH+b];
    const float4* p4 = (const float4*)pred;
    const float4* t4 = (const float4*)tgt;
    size_t base = (size_t)b*(NPIX/4) + (size_t)blockIdx.x*(NPIX/4/HGX);
    for (int it = 0; it < HITER; ++it) {
        size_t idx = base + (size_t)it*256 + tid;
        float4 pv = p4[idx], tv = t4[idx];
        float pa[4] = {pv.x, pv.y, pv.z, pv.w};
        float ta[4] = {tv.x, tv.y, tv.z, tv.w};
#pragma unroll
        for (int j = 0; j < 4; ++j) {
            if (ta[j] > 0.f) {
                uint32_t kp = fkey(pa[j]), kt = fkey(ta[j]);
                if ((kp >> 21) == b1p) { uint32_t bin=(kp>>10)&2047u; atomicAdd(&cP[bin],1u); atomicAdd(&sP[bin],pa[j]); }
                if ((kt >> 21) == b1t) { uint32_t bin=(kt>>10)&2047u; atomicAdd(&cT[bin],1u); atomicAdd(&sT[bin],ta[j]); }
            }
        }
    }
    __syncthreads();
    for (int i = tid; i < BINS2; i += 256) {
        if (cP[i]) { atomicAdd(&cnt[(size_t)b*BINS2+i], cP[i]); atomicAdd(&sum[(size_t)b*BINS2+i], sP[i]); }
        if (cT[i]) { atomicAdd(&cnt[(size_t)(NBATCH+b)*BINS2+i], cT[i]); atomicAdd(&sum[(size_t)(NBATCH+b)*BINS2+i], sT[i]); }
    }
}

__global__ __launch_bounds__(256) void k_medhist3(const float* __restrict__ pred, const float* __restrict__ tgt,
                                                  const uint32_t* __restrict__ b1arr, const uint32_t* __restrict__ b2arr,
                                                  uint32_t* __restrict__ cnt, float* __restrict__ sum) {
    __shared__ uint32_t cP[BINS3], cT[BINS3];
    __shared__ float sP[BINS3], sT[BINS3];
    const int tid = threadIdx.x;
    for (int i = tid; i < BINS3; i += 256) { cP[i]=0u; cT[i]=0u; sP[i]=0.f; sT[i]=0.f; }
    __syncthreads();
    const int b = blockIdx.y;
    const uint32_t t22p = (b1arr[b]<<11) | b2arr[b];
    const uint32_t t22t = (b1arr[NBATCH+b]<<11) | b2arr[NBATCH+b];
    const float4* p4 = (const float4*)pred;
    const float4* t4 = (const float4*)tgt;
    size_t base = (size_t)b*(NPIX/4) + (size_t)blockIdx.x*(NPIX/4/HGX);
    for (int it = 0; it < HITER; ++it) {
        size_t idx = base + (size_t)it*256 + tid;
        float4 pv = p4[idx], tv = t4[idx];
        float pa[4] = {pv.x, pv.y, pv.z, pv.w};
        float ta[4] = {tv.x, tv.y, tv.z, tv.w};
#pragma unroll
        for (int j = 0; j < 4; ++j) {
            if (ta[j] > 0.f) {
                uint32_t kp = fkey(pa[j]), kt = fkey(ta[j]);
                if ((kp >> 10) == t22p) { uint32_t bin=kp&1023u; atomicAdd(&cP[bin],1u); atomicAdd(&sP[bin],pa[j]); }
                if ((kt >> 10) == t22t) { uint32_t bin=kt&1023u; atomicAdd(&cT[bin],1u); atomicAdd(&sT[bin],ta[j]); }
            }
        }
    }
    __syncthreads();
    for (int i = tid; i < BINS3; i += 256) {
        if (cP[i]) { atomicAdd(&cnt[(size_t)b*BINS3+i], cP[i]); atomicAdd(&sum[(size_t)b*BINS3+i], sP[i]); }
        if (cT[i]) { atomicAdd(&cnt[(size_t)(NBATCH+b)*BINS3+i], cT[i]); atomicAdd(&sum[(size_t)(NBATCH+b)*BINS3+i], sT[i]); }
    }
}

// ===== residual passes. Mask is the NORMALIZED-target mask: t_n > 0  <=>  t > median_t.
// v = mask ? |p_n - t_n| : 0, over ALL N elements (zeros participate in the rank).
__device__ __forceinline__ float res_val(float p, float t, float sp, float ivp, float st, float ivt) {
    return (t > st) ? fabsf((p - sp)*ivp - (t - st)*ivt) : 0.f;
}

__global__ __launch_bounds__(256) void k_reshist1(const float* __restrict__ pred, const float* __restrict__ tgt,
                                                  const float* __restrict__ shiftA, const float* __restrict__ sclA,
                                                  uint32_t* __restrict__ cnt, float* __restrict__ sum) {
    __shared__ uint32_t cR[BINS1];
    __shared__ float sR[BINS1];
    const int tid = threadIdx.x;
    for (int i = tid; i < BINS1; i += 256) { cR[i]=0u; sR[i]=0.f; }
    __syncthreads();
    const int b = blockIdx.y;
    const float sp = shiftA[b], st = shiftA[NBATCH+b];
    const float ivp = 1.f/sclA[b], ivt = 1.f/sclA[NBATCH+b];
    const float4* p4 = (const float4*)pred;
    const float4* t4 = (const float4*)tgt;
    size_t base = (size_t)b*(NPIX/4) + (size_t)blockIdx.x*(NPIX/4/HGX);
    for (int it = 0; it < HITER; ++it) {
        size_t idx = base + (size_t)it*256 + tid;
        float4 pv = p4[idx], tv = t4[idx];
        float pa[4] = {pv.x, pv.y, pv.z, pv.w};
        float ta[4] = {tv.x, tv.y, tv.z, tv.w};
#pragma unroll
        for (int j = 0; j < 4; ++j) {
            float v = res_val(pa[j], ta[j], sp, ivp, st, ivt);
            uint32_t k = fkey(v) >> 21;
            atomicAdd(&cR[k], 1u); atomicAdd(&sR[k], v);
        }
    }
    __syncthreads();
    for (int i = tid; i < BINS1; i += 256) {
        if (cR[i]) { atomicAdd(&cnt[(size_t)b*BINS1+i], cR[i]); atomicAdd(&sum[(size_t)b*BINS1+i], sR[i]); }
    }
}

__global__ __launch_bounds__(256) void k_reshist2(const float* __restrict__ pred, const float* __restrict__ tgt,
                                                  const float* __restrict__ shiftA, const float* __restrict__ sclA,
                                                  const uint32_t* __restrict__ b1arr,
                                                  uint32_t* __restrict__ cnt, float* __restrict__ sum) {
    __shared__ uint32_t cR[BINS2];
    __shared__ float sR[BINS2];
    const int tid = threadIdx.x;
    for (int i = tid; i < BINS2; i += 256) { cR[i]=0u; sR[i]=0.f; }
    __syncthreads();
    const int b = blockIdx.y;
    const float sp = shiftA[b], st = shiftA[NBATCH+b];
    const float ivp = 1.f/sclA[b], ivt = 1.f/sclA[NBATCH+b];
    const uint32_t rb1 = b1arr[b];
    const float4* p4 = (const float4*)pred;
    const float4* t4 = (const float4*)tgt;
    size_t base = (size_t)b*(NPIX/4) + (size_t)blockIdx.x*(NPIX/4/HGX);
    for (int it = 0; it < HITER; ++it) {
        size_t idx = base + (size_t)it*256 + tid;
        float4 pv = p4[idx], tv = t4[idx];
        float pa[4] = {pv.x, pv.y, pv.z, pv.w};
        float ta[4] = {tv.x, tv.y, tv.z, tv.w};
#pragma unroll
        for (int j = 0; j < 4; ++j) {
            float v = res_val(pa[j], ta[j], sp, ivp, st, ivt);
            uint32_t k = fkey(v);
            if ((k >> 21) == rb1) { uint32_t bin=(k>>10)&2047u; atomicAdd(&cR[bin],1u); atomicAdd(&sR[bin],v); }
        }
    }
    __syncthreads();
    for (int i = tid; i < BINS2; i += 256) {
        if (cR[i]) { atomicAdd(&cnt[(size_t)b*BINS2+i], cR[i]); atomicAdd(&sum[(size_t)b*BINS2+i], sR[i]); }
    }
}

__global__ __launch_bounds__(256) void k_reshist3(const float* __restrict__ pred, const float* __restrict__ tgt,
                                                  const float* __restrict__ shiftA, const float* __restrict__ sclA,
                                                  const uint32_t* __restrict__ b1arr, const uint32_t* __restrict__ b2arr,
                                                  uint32_t* __restrict__ cnt, float* __restrict__ sum) {
    __shared__ uint32_t cR[BINS3];
    __shared__ float sR[BINS3];
    const int tid = threadIdx.x;
    for (int i = tid; i < BINS3; i += 256) { cR[i]=0u; sR[i]=0.f; }
    __syncthreads();
    const int b = blockIdx.y;
    const float sp = shiftA[b], st = shiftA[NBATCH+b];
    const float ivp = 1.f/sclA[b], ivt = 1.f/sclA[NBATCH+b];
    const uint32_t t22 = (b1arr[b]<<11) | b2arr[b];
    const float4* p4 = (const float4*)pred;
    const float4* t4 = (const float4*)tgt;
    size_t base = (size_t)b*(NPIX/4) + (size_t)blockIdx.x*(NPIX/4/HGX);
    for (int it = 0; it < HITER; ++it) {
        size_t idx = base + (size_t)it*256 + tid;
        float4 pv = p4[idx], tv = t4[idx];
        float pa[4] = {pv.x, pv.y, pv.z, pv.w};
        float ta[4] = {tv.x, tv.y, tv.z, tv.w};
#pragma unroll
        for (int j = 0; j < 4; ++j) {
            float v = res_val(pa[j], ta[j], sp, ivp, st, ivt);
            uint32_t k = fkey(v);
            if ((k >> 10) == t22) { uint32_t bin=k&1023u; atomicAdd(&cR[bin],1u); atomicAdd(&sR[bin],v); }
        }
    }
    __syncthreads();
    for (int i = tid; i < BINS3; i += 256) {
        if (cR[i]) { atomicAdd(&cnt[(size_t)b*BINS3+i], cR[i]); atomicAdd(&sum[(size_t)b*BINS3+i], sR[i]); }
    }
}

// ================= generic level select =================
// mode 0 = median (128 problems: tensor*64+batch), mode 1 = residual (64 problems)
__global__ __launch_bounds__(256) void k_select(uint32_t* wu, float* wf,
                                                const uint32_t* cnt, const float* sum,
                                                int nbins, int level, int mode) {
    const int q = blockIdx.x;
    const int tid = threadIdx.x;
    const int bpt = nbins >> 8;
    const uint32_t* c = cnt + (size_t)q*nbins + (size_t)tid*bpt;
    const float*    s = sum + (size_t)q*nbins + (size_t)tid*bpt;
    uint32_t tcnt = 0; float tsum = 0.f;
    for (int j = 0; j < bpt; ++j) { tcnt += c[j]; tsum += s[j]; }
    __shared__ uint32_t sc[256];
    __shared__ float ss[256];
    sc[tid] = tcnt; ss[tid] = tsum;
    __syncthreads();
    for (int off = 1; off < 256; off <<= 1) {
        uint32_t u = 0; float f = 0.f;
        if (tid >= off) { u = sc[tid-off]; f = ss[tid-off]; }
        __syncthreads();
        if (tid >= off) { sc[tid] += u; ss[tid] += f; }
        __syncthreads();
    }
    const uint32_t total = sc[255];
    const float totsum = ss[255];
    const uint32_t excl = sc[tid] - tcnt;
    const float exclS = ss[tid] - tsum;

    uint32_t r;
    if (level == 0) {
        if (mode == 0) {
            if (tid == 0) { wu[ST_N+q] = total; wf[ST_STOT+q] = totsum; }
            r = total ? (total - 1u) / 2u : 0u;   // lower median rank
        } else {
            uint32_t n2 = wu[ST_N2 + NBATCH + q]; // #{t > median_t} = trim/grad mask count
            uint32_t mi = (uint32_t)NPIX - n2 + TRIM_IDX;
            if (mi > (uint32_t)NPIX - 1u) mi = (uint32_t)NPIX - 1u;
            r = mi;
        }
    } else {
        r = wu[ST_RANK+q];
    }
    __syncthreads();  // all threads have read ST_RANK before the owner overwrites it

    if (total > 0u && excl <= r && r < excl + tcnt) {
        uint32_t cum = excl; float fs = exclS;
        for (int j = 0; j < bpt; ++j) {
            uint32_t cj = c[j];
            if (r < cum + cj) {
                uint32_t bidx = (uint32_t)(tid*bpt + j);
                float sj = s[j];
                if (level == 0) {
                    wu[ST_B1+q] = bidx; wu[ST_RANK+q] = r - cum; wu[ST_CLT+q] = cum; wf[ST_SLT+q] = fs;
                } else if (level == 1) {
                    wu[ST_B2+q] = bidx; wu[ST_RANK+q] = r - cum; wu[ST_CLT+q] += cum; wf[ST_SLT+q] += fs;
                } else {
                    if (mode == 0) {
                        uint32_t key = (wu[ST_B1+q] << 21) | (wu[ST_B2+q] << 10) | bidx;
                        float m = funkey(key);                     // exact median value
                        uint32_t n = wu[ST_N+q];
                        uint32_t c_le = wu[ST_CLT+q] + cum + cj;   // count of x <= m (masked)
                        float S_le = wf[ST_SLT+q] + fs + sj;       // sum of x <= m
                        float stot = wf[ST_STOT+q];
                        float mad = ((2.f*(float)c_le - (float)n)*m + stot - 2.f*S_le) / (float)(n ? n : 1u);
                        float scale = (mad > 0.f) ? mad : 1.f;
                        wf[ST_SHIFT+q] = m; wf[ST_SCL+q] = scale;
                        wu[ST_N2+q] = n - c_le;                    // #{x > median} among all N
                    } else {
                        float S_le = wf[ST_SLT+q] + fs + sj;       // sum of res <= thr (ties incl.)
                        uint32_t n2 = wu[ST_N2 + NBATCH + q];
                        wf[ST_TRIMA+q] = n2 ? (S_le / (float)(2u*n2)) : 0.f;
                    }
                }
                break;
            }
            cum += cj; fs += s[j];
        }
    }
    if (tid == 0 && total == 0u) {  // degenerate guard (no masked elements)
        if (level == 0)      { wu[ST_B1+q]=0; wu[ST_RANK+q]=0; wu[ST_CLT+q]=0; wf[ST_SLT+q]=0.f; }
        else if (level == 1) { wu[ST_B2+q]=0; }
        else {
            if (mode == 0) { wf[ST_SHIFT+q]=0.f; wf[ST_SCL+q]=1.f; wu[ST_N2+q]=0u; }
            else           { wf[ST_TRIMA+q]=0.f; }
        }
    }
}

// ===== fused 4-scale gradient loss (mask = normalized-target mask: t > median_t) =====
__global__ __launch_bounds__(256) void k_grad(const float* __restrict__ pred, const float* __restrict__ tgt,
                                              const float* __restrict__ shiftA, const float* __restrict__ sclA,
                                              float* __restrict__ gsum, uint32_t* __restrict__ gcnt) {
    const int b = blockIdx.y;
    const int pix = blockIdx.x*256 + threadIdx.x;
    const int y = pix >> 9, x = pix & 511;
    const size_t base = (size_t)b * NPIX;
    const float sp = shiftA[b], st = shiftA[NBATCH+b];
    const float ivp = 1.f/sclA[b], ivt = 1.f/sclA[NBATCH+b];
    const float t0 = tgt[base+pix], p0 = pred[base+pix];
    const bool m0 = t0 > st;
    const float d0 = (p0 - sp)*ivp - (t0 - st)*ivt;
    float gs[4] = {0.f,0.f,0.f,0.f};
    uint32_t gc[4] = {0u,0u,0u,0u};
#pragma unroll
    for (int sL = 0; sL < 4; ++sL) {
        const int step = 1 << sL;
        if ((y & (step-1)) || (x & (step-1))) continue;
        if (m0) gc[sL] = 1u;
        if (x + step < WW) {
            float t1 = tgt[base+pix+step], p1 = pred[base+pix+step];
            if (m0 && t1 > st) {
                float d1 = (p1 - sp)*ivp - (t1 - st)*ivt;
                gs[sL] += fabsf(d1 - d0);
            }
        }
        if (y + step < HH) {
            float t2 = tgt[base+pix+step*WW], p2 = pred[base+pix+step*WW];
            if (m0 && t2 > st) {
                float d2 = (p2 - sp)*ivp - (t2 - st)*ivt;
                gs[sL] += fabsf(d2 - d0);
            }
        }
    }
    __shared__ float ls[4][4];
    __shared__ uint32_t lc[4][4];
    const int lane = threadIdx.x & 63, wv = threadIdx.x >> 6;
#pragma unroll
    for (int sL = 0; sL < 4; ++sL) {
        float v = gs[sL]; uint32_t cc = gc[sL];
        for (int off = 32; off; off >>= 1) { v += __shfl_down(v, off, 64); cc += __shfl_down(cc, off, 64); }
        if (lane == 0) { ls[sL][wv] = v; lc[sL][wv] = cc; }
    }
    __syncthreads();
    if (threadIdx.x < 4) {
        const int sL = threadIdx.x;
        float v = ls[sL][0] + ls[sL][1] + ls[sL][2] + ls[sL][3];
        uint32_t cc = lc[sL][0] + lc[sL][1] + lc[sL][2] + lc[sL][3];
        if (v != 0.f) atomicAdd(&gsum[sL*NBATCH + b], v);
        if (cc)       atomicAdd(&gcnt[sL*NBATCH + b], cc);
    }
}

// ================= final combine =================
__global__ void k_final(const float* __restrict__ trima, const float* __restrict__ gsum,
                        const uint32_t* __restrict__ gcnt, float* __restrict__ out) {
    const int b = threadIdx.x;  // 64 threads, one wave
    float v = trima[b];
#pragma unroll
    for (int sL = 0; sL < 4; ++sL) {
        uint32_t cc = gcnt[sL*NBATCH + b];
        float g = cc ? gsum[sL*NBATCH + b] / (float)cc : 0.f;
        v += 0.5f * g;   // ALPHA = 0.5
    }
    for (int off = 32; off; off >>= 1) v += __shfl_down(v, off, 64);
    if (b == 0) out[0] = v * (1.f/64.f);
}

extern "C" void kernel_launch(void* const* d_in, const int* in_sizes, int n_in,
                              void* d_out, int out_size, void* d_ws, size_t ws_size,
                              hipStream_t stream) {
    const float* pred = (const float*)d_in[0];
    const float* tgt  = (const float*)d_in[1];
    uint32_t* wu = (uint32_t*)d_ws;
    float*    wf = (float*)d_ws;
    if (ws_size < (size_t)WS_TOTAL * 4) return;  // ~5.26 MB needed

    hipMemsetAsync(d_ws, 0, (size_t)WS_TOTAL * 4, stream);
    dim3 hg(HGX, NBATCH);

    // --- medians + robust scales for pred & tgt (3-level radix select, sum-augmented) ---
    k_medhist1<<<hg, 256, 0, stream>>>(pred, tgt, wu + OFF_C1, wf + OFF_S1);
    k_select<<<128, 256, 0, stream>>>(wu, wf, wu + OFF_C1, wf + OFF_S1, BINS1, 0, 0);
    k_medhist2<<<hg, 256, 0, stream>>>(pred, tgt, wu + ST_B1, wu + OFF_C2, wf + OFF_S2);
    k_select<<<128, 256, 0, stream>>>(wu, wf, wu + OFF_C2, wf + OFF_S2, BINS2, 1, 0);
    k_medhist3<<<hg, 256, 0, stream>>>(pred, tgt, wu + ST_B1, wu + ST_B2, wu + OFF_C3, wf + OFF_S3);
    k_select<<<128, 256, 0, stream>>>(wu, wf, wu + OFF_C3, wf + OFF_S3, BINS3, 2, 0);

    // --- trimmed MAE: rank-select over residuals + prefix sum (re-zero hist region only) ---
    hipMemsetAsync(d_ws, 0, (size_t)OFF_STATE * 4, stream);
    k_reshist1<<<hg, 256, 0, stream>>>(pred, tgt, wf + ST_SHIFT, wf + ST_SCL, wu + OFF_C1, wf + OFF_S1);
    k_select<<<64, 256, 0, stream>>>(wu, wf, wu + OFF_C1, wf + OFF_S1, BINS1, 0, 1);
    k_reshist2<<<hg, 256, 0, stream>>>(pred, tgt, wf + ST_SHIFT, wf + ST_SCL, wu + ST_B1, wu + OFF_C2, wf + OFF_S2);
    k_select<<<64, 256, 0, stream>>>(wu, wf, wu + OFF_C2, wf + OFF_S2, BINS2, 1, 1);
    k_reshist3<<<hg, 256, 0, stream>>>(pred, tgt, wf + ST_SHIFT, wf + ST_SCL, wu + ST_B1, wu + ST_B2, wu + OFF_C3, wf + OFF_S3);
    k_select<<<64, 256, 0, stream>>>(wu, wf, wu + OFF_C3, wf + OFF_S3, BINS3, 2, 1);

    // --- fused multiscale gradient loss ---
    k_grad<<<dim3(NPIX/256, NBATCH), 256, 0, stream>>>(pred, tgt, wf + ST_SHIFT, wf + ST_SCL,
                                                       wf + ST_GSUM, wu + ST_GCNT);
    // --- combine ---
    k_final<<<1, 64, 0, stream>>>(wf + ST_TRIMA, wf + ST_GSUM, wu + ST_GCNT, (float*)d_out);
}

// Round 3
// 507.590 us; speedup vs baseline: 2.1024x; 2.1024x over previous
//
#include <hip/hip_runtime.h>
#include <stdint.h>

#define NBATCH 64
#define HH 512
#define WW 512
#define NPIX 262144            // 512*512
#define BINS1 2048             // key bits [31:21]
#define BINS2 2048             // key bits [20:10]
#define BINS3 1024             // key bits [9:0]
#define TRIM_IDX 209715u       // int((1-0.2)*262144)
#define HGX 16                 // hist blocks per batch
#define HITER (NPIX/4/HGX/256) // float4 iters per hist block

// ---------------- workspace layout (u32 units) ----------------
#define SZ_C1 (2*NBATCH*BINS1)
#define OFF_C1 0
#define OFF_S1 (OFF_C1 + SZ_C1)
#define OFF_C2 (OFF_S1 + SZ_C1)
#define OFF_S2 (OFF_C2 + SZ_C1)
#define OFF_C3 (OFF_S2 + SZ_C1)
#define SZ_C3 (2*NBATCH*BINS3)
#define OFF_S3 (OFF_C3 + SZ_C3)
#define OFF_STATE (OFF_S3 + SZ_C3)
// state (survives the mid-pipeline hist re-zero):
#define ST_N     (OFF_STATE)        // u32 [128]  masked count per (tensor,batch)
#define ST_N2    (ST_N + 128)       // u32 [128]  count of x > median (mask for trim/grad)
#define ST_B1    (ST_N2 + 128)      // u32 [128]
#define ST_B2    (ST_B1 + 128)      // u32 [128]
#define ST_RANK  (ST_B2 + 128)      // u32 [128]
#define ST_CLT   (ST_RANK + 128)    // u32 [128]  count of keys strictly below bucket
#define ST_SLT   (ST_CLT + 128)     // f32 [128]  sum of values strictly below bucket
#define ST_STOT  (ST_SLT + 128)     // f32 [128]
#define ST_SHIFT (ST_STOT + 128)    // f32 [128]  median per (tensor,batch)
#define ST_SCL   (ST_SHIFT + 128)   // f32 [128]  robust scale
#define ST_TRIMA (ST_SCL + 128)     // f32 [64]   per-batch trimmed loss
#define ST_GSUM  (ST_TRIMA + 64)    // f32 [4*64] gradient sums
#define ST_GCNT  (ST_GSUM + 256)    // u32 [4*64] gradient mask counts
#define WS_TOTAL (ST_GCNT + 256)

// gradient tile geometry
#define GTW 128                // interior tile width
#define GTH 64                 // interior tile height
#define GHALO 8
#define GLW (GTW + GHALO)      // 136 loaded cols
#define GLH (GTH + GHALO)      // 72 loaded rows
#define GL4 (GLW/4)            // 34 float4 per row

// order-preserving float -> u32 key (total order incl. negatives)
__device__ __forceinline__ uint32_t fkey(float x) {
    uint32_t u = __float_as_uint(x);
    return (u & 0x80000000u) ? ~u : (u | 0x80000000u);
}
__device__ __forceinline__ float funkey(uint32_t k) {
    return __uint_as_float((k & 0x80000000u) ? (k & 0x7fffffffu) : ~k);
}

// ================= median histogram passes (both tensors, masked by tgt>0) ===========
__global__ __launch_bounds__(256) void k_medhist1(const float* __restrict__ pred, const float* __restrict__ tgt,
                                                  uint32_t* __restrict__ cnt, float* __restrict__ sum) {
    __shared__ uint32_t cP[BINS1], cT[BINS1];
    __shared__ float sP[BINS1], sT[BINS1];
    const int tid = threadIdx.x;
    for (int i = tid; i < BINS1; i += 256) { cP[i]=0u; cT[i]=0u; sP[i]=0.f; sT[i]=0.f; }
    __syncthreads();
    const int b = blockIdx.y;
    const float4* p4 = (const float4*)pred;
    const float4* t4 = (const float4*)tgt;
    size_t base = (size_t)b*(NPIX/4) + (size_t)blockIdx.x*(NPIX/4/HGX);
    for (int it = 0; it < HITER; ++it) {
        size_t idx = base + (size_t)it*256 + tid;
        float4 pv = p4[idx], tv = t4[idx];
        float pa[4] = {pv.x, pv.y, pv.z, pv.w};
        float ta[4] = {tv.x, tv.y, tv.z, tv.w};
#pragma unroll
        for (int j = 0; j < 4; ++j) {
            if (ta[j] > 0.f) {
                uint32_t kp = fkey(pa[j]) >> 21, kt = fkey(ta[j]) >> 21;
                atomicAdd(&cP[kp], 1u); atomicAdd(&sP[kp], pa[j]);
                atomicAdd(&cT[kt], 1u); atomicAdd(&sT[kt], ta[j]);
            }
        }
    }
    __syncthreads();
    for (int i = tid; i < BINS1; i += 256) {
        if (cP[i]) { atomicAdd(&cnt[(size_t)b*BINS1+i], cP[i]); atomicAdd(&sum[(size_t)b*BINS1+i], sP[i]); }
        if (cT[i]) { atomicAdd(&cnt[(size_t)(NBATCH+b)*BINS1+i], cT[i]); atomicAdd(&sum[(size_t)(NBATCH+b)*BINS1+i], sT[i]); }
    }
}

__global__ __launch_bounds__(256) void k_medhist2(const float* __restrict__ pred, const float* __restrict__ tgt,
                                                  const uint32_t* __restrict__ b1arr,
                                                  uint32_t* __restrict__ cnt, float* __restrict__ sum) {
    __shared__ uint32_t cP[BINS2], cT[BINS2];
    __shared__ float sP[BINS2], sT[BINS2];
    const int tid = threadIdx.x;
    for (int i = tid; i < BINS2; i += 256) { cP[i]=0u; cT[i]=0u; sP[i]=0.f; sT[i]=0.f; }
    __syncthreads();
    const int b = blockIdx.y;
    const uint32_t b1p = b1arr[b], b1t = b1arr[NBATCH+b];
    const float4* p4 = (const float4*)pred;
    const float4* t4 = (const float4*)tgt;
    size_t base = (size_t)b*(NPIX/4) + (size_t)blockIdx.x*(NPIX/4/HGX);
    for (int it = 0; it < HITER; ++it) {
        size_t idx = base + (size_t)it*256 + tid;
        float4 pv = p4[idx], tv = t4[idx];
        float pa[4] = {pv.x, pv.y, pv.z, pv.w};
        float ta[4] = {tv.x, tv.y, tv.z, tv.w};
#pragma unroll
        for (int j = 0; j < 4; ++j) {
            if (ta[j] > 0.f) {
                uint32_t kp = fkey(pa[j]), kt = fkey(ta[j]);
                if ((kp >> 21) == b1p) { uint32_t bin=(kp>>10)&2047u; atomicAdd(&cP[bin],1u); atomicAdd(&sP[bin],pa[j]); }
                if ((kt >> 21) == b1t) { uint32_t bin=(kt>>10)&2047u; atomicAdd(&cT[bin],1u); atomicAdd(&sT[bin],ta[j]); }
            }
        }
    }
    __syncthreads();
    for (int i = tid; i < BINS2; i += 256) {
        if (cP[i]) { atomicAdd(&cnt[(size_t)b*BINS2+i], cP[i]); atomicAdd(&sum[(size_t)b*BINS2+i], sP[i]); }
        if (cT[i]) { atomicAdd(&cnt[(size_t)(NBATCH+b)*BINS2+i], cT[i]); atomicAdd(&sum[(size_t)(NBATCH+b)*BINS2+i], sT[i]); }
    }
}

__global__ __launch_bounds__(256) void k_medhist3(const float* __restrict__ pred, const float* __restrict__ tgt,
                                                  const uint32_t* __restrict__ b1arr, const uint32_t* __restrict__ b2arr,
                                                  uint32_t* __restrict__ cnt, float* __restrict__ sum) {
    __shared__ uint32_t cP[BINS3], cT[BINS3];
    __shared__ float sP[BINS3], sT[BINS3];
    const int tid = threadIdx.x;
    for (int i = tid; i < BINS3; i += 256) { cP[i]=0u; cT[i]=0u; sP[i]=0.f; sT[i]=0.f; }
    __syncthreads();
    const int b = blockIdx.y;
    const uint32_t t22p = (b1arr[b]<<11) | b2arr[b];
    const uint32_t t22t = (b1arr[NBATCH+b]<<11) | b2arr[NBATCH+b];
    const float4* p4 = (const float4*)pred;
    const float4* t4 = (const float4*)tgt;
    size_t base = (size_t)b*(NPIX/4) + (size_t)blockIdx.x*(NPIX/4/HGX);
    for (int it = 0; it < HITER; ++it) {
        size_t idx = base + (size_t)it*256 + tid;
        float4 pv = p4[idx], tv = t4[idx];
        float pa[4] = {pv.x, pv.y, pv.z, pv.w};
        float ta[4] = {tv.x, tv.y, tv.z, tv.w};
#pragma unroll
        for (int j = 0; j < 4; ++j) {
            if (ta[j] > 0.f) {
                uint32_t kp = fkey(pa[j]), kt = fkey(ta[j]);
                if ((kp >> 10) == t22p) { uint32_t bin=kp&1023u; atomicAdd(&cP[bin],1u); atomicAdd(&sP[bin],pa[j]); }
                if ((kt >> 10) == t22t) { uint32_t bin=kt&1023u; atomicAdd(&cT[bin],1u); atomicAdd(&sT[bin],ta[j]); }
            }
        }
    }
    __syncthreads();
    for (int i = tid; i < BINS3; i += 256) {
        if (cP[i]) { atomicAdd(&cnt[(size_t)b*BINS3+i], cP[i]); atomicAdd(&sum[(size_t)b*BINS3+i], sP[i]); }
        if (cT[i]) { atomicAdd(&cnt[(size_t)(NBATCH+b)*BINS3+i], cT[i]); atomicAdd(&sum[(size_t)(NBATCH+b)*BINS3+i], sT[i]); }
    }
}

// ===== residual passes. Mask is the NORMALIZED-target mask: t_n > 0  <=>  t > median_t.
// v = mask ? |p_n - t_n| : 0, over ALL N elements (zeros participate in the rank).
__device__ __forceinline__ float res_val(float p, float t, float sp, float ivp, float st, float ivt) {
    return (t > st) ? fabsf((p - sp)*ivp - (t - st)*ivt) : 0.f;
}

__global__ __launch_bounds__(256) void k_reshist1(const float* __restrict__ pred, const float* __restrict__ tgt,
                                                  const float* __restrict__ shiftA, const float* __restrict__ sclA,
                                                  uint32_t* __restrict__ cnt, float* __restrict__ sum) {
    __shared__ uint32_t cR[BINS1];
    __shared__ float sR[BINS1];
    const int tid = threadIdx.x;
    for (int i = tid; i < BINS1; i += 256) { cR[i]=0u; sR[i]=0.f; }
    __syncthreads();
    const int b = blockIdx.y;
    const float sp = shiftA[b], st = shiftA[NBATCH+b];
    const float ivp = 1.f/sclA[b], ivt = 1.f/sclA[NBATCH+b];
    const float4* p4 = (const float4*)pred;
    const float4* t4 = (const float4*)tgt;
    size_t base = (size_t)b*(NPIX/4) + (size_t)blockIdx.x*(NPIX/4/HGX);
    for (int it = 0; it < HITER; ++it) {
        size_t idx = base + (size_t)it*256 + tid;
        float4 pv = p4[idx], tv = t4[idx];
        float pa[4] = {pv.x, pv.y, pv.z, pv.w};
        float ta[4] = {tv.x, tv.y, tv.z, tv.w};
#pragma unroll
        for (int j = 0; j < 4; ++j) {
            float v = res_val(pa[j], ta[j], sp, ivp, st, ivt);
            uint32_t k = fkey(v) >> 21;
            atomicAdd(&cR[k], 1u); atomicAdd(&sR[k], v);
        }
    }
    __syncthreads();
    for (int i = tid; i < BINS1; i += 256) {
        if (cR[i]) { atomicAdd(&cnt[(size_t)b*BINS1+i], cR[i]); atomicAdd(&sum[(size_t)b*BINS1+i], sR[i]); }
    }
}

__global__ __launch_bounds__(256) void k_reshist2(const float* __restrict__ pred, const float* __restrict__ tgt,
                                                  const float* __restrict__ shiftA, const float* __restrict__ sclA,
                                                  const uint32_t* __restrict__ b1arr,
                                                  uint32_t* __restrict__ cnt, float* __restrict__ sum) {
    __shared__ uint32_t cR[BINS2];
    __shared__ float sR[BINS2];
    const int tid = threadIdx.x;
    for (int i = tid; i < BINS2; i += 256) { cR[i]=0u; sR[i]=0.f; }
    __syncthreads();
    const int b = blockIdx.y;
    const float sp = shiftA[b], st = shiftA[NBATCH+b];
    const float ivp = 1.f/sclA[b], ivt = 1.f/sclA[NBATCH+b];
    const uint32_t rb1 = b1arr[b];
    const float4* p4 = (const float4*)pred;
    const float4* t4 = (const float4*)tgt;
    size_t base = (size_t)b*(NPIX/4) + (size_t)blockIdx.x*(NPIX/4/HGX);
    for (int it = 0; it < HITER; ++it) {
        size_t idx = base + (size_t)it*256 + tid;
        float4 pv = p4[idx], tv = t4[idx];
        float pa[4] = {pv.x, pv.y, pv.z, pv.w};
        float ta[4] = {tv.x, tv.y, tv.z, tv.w};
#pragma unroll
        for (int j = 0; j < 4; ++j) {
            float v = res_val(pa[j], ta[j], sp, ivp, st, ivt);
            uint32_t k = fkey(v);
            if ((k >> 21) == rb1) { uint32_t bin=(k>>10)&2047u; atomicAdd(&cR[bin],1u); atomicAdd(&sR[bin],v); }
        }
    }
    __syncthreads();
    for (int i = tid; i < BINS2; i += 256) {
        if (cR[i]) { atomicAdd(&cnt[(size_t)b*BINS2+i], cR[i]); atomicAdd(&sum[(size_t)b*BINS2+i], sR[i]); }
    }
}

__global__ __launch_bounds__(256) void k_reshist3(const float* __restrict__ pred, const float* __restrict__ tgt,
                                                  const float* __restrict__ shiftA, const float* __restrict__ sclA,
                                                  const uint32_t* __restrict__ b1arr, const uint32_t* __restrict__ b2arr,
                                                  uint32_t* __restrict__ cnt, float* __restrict__ sum) {
    __shared__ uint32_t cR[BINS3];
    __shared__ float sR[BINS3];
    const int tid = threadIdx.x;
    for (int i = tid; i < BINS3; i += 256) { cR[i]=0u; sR[i]=0.f; }
    __syncthreads();
    const int b = blockIdx.y;
    const float sp = shiftA[b], st = shiftA[NBATCH+b];
    const float ivp = 1.f/sclA[b], ivt = 1.f/sclA[NBATCH+b];
    const uint32_t t22 = (b1arr[b]<<11) | b2arr[b];
    const float4* p4 = (const float4*)pred;
    const float4* t4 = (const float4*)tgt;
    size_t base = (size_t)b*(NPIX/4) + (size_t)blockIdx.x*(NPIX/4/HGX);
    for (int it = 0; it < HITER; ++it) {
        size_t idx = base + (size_t)it*256 + tid;
        float4 pv = p4[idx], tv = t4[idx];
        float pa[4] = {pv.x, pv.y, pv.z, pv.w};
        float ta[4] = {tv.x, tv.y, tv.z, tv.w};
#pragma unroll
        for (int j = 0; j < 4; ++j) {
            float v = res_val(pa[j], ta[j], sp, ivp, st, ivt);
            uint32_t k = fkey(v);
            if ((k >> 10) == t22) { uint32_t bin=k&1023u; atomicAdd(&cR[bin],1u); atomicAdd(&sR[bin],v); }
        }
    }
    __syncthreads();
    for (int i = tid; i < BINS3; i += 256) {
        if (cR[i]) { atomicAdd(&cnt[(size_t)b*BINS3+i], cR[i]); atomicAdd(&sum[(size_t)b*BINS3+i], sR[i]); }
    }
}

// ================= generic level select =================
__global__ __launch_bounds__(256) void k_select(uint32_t* wu, float* wf,
                                                const uint32_t* cnt, const float* sum,
                                                int nbins, int level, int mode) {
    const int q = blockIdx.x;
    const int tid = threadIdx.x;
    const int bpt = nbins >> 8;
    const uint32_t* c = cnt + (size_t)q*nbins + (size_t)tid*bpt;
    const float*    s = sum + (size_t)q*nbins + (size_t)tid*bpt;
    uint32_t tcnt = 0; float tsum = 0.f;
    for (int j = 0; j < bpt; ++j) { tcnt += c[j]; tsum += s[j]; }
    __shared__ uint32_t sc[256];
    __shared__ float ss[256];
    sc[tid] = tcnt; ss[tid] = tsum;
    __syncthreads();
    for (int off = 1; off < 256; off <<= 1) {
        uint32_t u = 0; float f = 0.f;
        if (tid >= off) { u = sc[tid-off]; f = ss[tid-off]; }
        __syncthreads();
        if (tid >= off) { sc[tid] += u; ss[tid] += f; }
        __syncthreads();
    }
    const uint32_t total = sc[255];
    const float totsum = ss[255];
    const uint32_t excl = sc[tid] - tcnt;
    const float exclS = ss[tid] - tsum;

    uint32_t r;
    if (level == 0) {
        if (mode == 0) {
            if (tid == 0) { wu[ST_N+q] = total; wf[ST_STOT+q] = totsum; }
            r = total ? (total - 1u) / 2u : 0u;   // lower median rank
        } else {
            uint32_t n2 = wu[ST_N2 + NBATCH + q]; // #{t > median_t} = trim/grad mask count
            uint32_t mi = (uint32_t)NPIX - n2 + TRIM_IDX;
            if (mi > (uint32_t)NPIX - 1u) mi = (uint32_t)NPIX - 1u;
            r = mi;
        }
    } else {
        r = wu[ST_RANK+q];
    }
    __syncthreads();  // all threads have read ST_RANK before the owner overwrites it

    if (total > 0u && excl <= r && r < excl + tcnt) {
        uint32_t cum = excl; float fs = exclS;
        for (int j = 0; j < bpt; ++j) {
            uint32_t cj = c[j];
            if (r < cum + cj) {
                uint32_t bidx = (uint32_t)(tid*bpt + j);
                float sj = s[j];
                if (level == 0) {
                    wu[ST_B1+q] = bidx; wu[ST_RANK+q] = r - cum; wu[ST_CLT+q] = cum; wf[ST_SLT+q] = fs;
                } else if (level == 1) {
                    wu[ST_B2+q] = bidx; wu[ST_RANK+q] = r - cum; wu[ST_CLT+q] += cum; wf[ST_SLT+q] += fs;
                } else {
                    if (mode == 0) {
                        uint32_t key = (wu[ST_B1+q] << 21) | (wu[ST_B2+q] << 10) | bidx;
                        float m = funkey(key);                     // exact median value
                        uint32_t n = wu[ST_N+q];
                        uint32_t c_le = wu[ST_CLT+q] + cum + cj;   // count of x <= m (masked)
                        float S_le = wf[ST_SLT+q] + fs + sj;       // sum of x <= m
                        float stot = wf[ST_STOT+q];
                        float mad = ((2.f*(float)c_le - (float)n)*m + stot - 2.f*S_le) / (float)(n ? n : 1u);
                        float scale = (mad > 0.f) ? mad : 1.f;
                        wf[ST_SHIFT+q] = m; wf[ST_SCL+q] = scale;
                        wu[ST_N2+q] = n - c_le;                    // #{x > median} among all N
                    } else {
                        float S_le = wf[ST_SLT+q] + fs + sj;       // sum of res <= thr (ties incl.)
                        uint32_t n2 = wu[ST_N2 + NBATCH + q];
                        wf[ST_TRIMA+q] = n2 ? (S_le / (float)(2u*n2)) : 0.f;
                    }
                }
                break;
            }
            cum += cj; fs += s[j];
        }
    }
    if (tid == 0 && total == 0u) {  // degenerate guard
        if (level == 0)      { wu[ST_B1+q]=0; wu[ST_RANK+q]=0; wu[ST_CLT+q]=0; wf[ST_SLT+q]=0.f; }
        else if (level == 1) { wu[ST_B2+q]=0; }
        else {
            if (mode == 0) { wf[ST_SHIFT+q]=0.f; wf[ST_SCL+q]=1.f; wu[ST_N2+q]=0u; }
            else           { wf[ST_TRIMA+q]=0.f; }
        }
    }
}

// ===== fused 4-scale gradient loss, LDS-tiled =====
// d = (p-sp)*ivp - (t-st)*ivt staged in LDS; NaN marks unmasked (t <= median_t).
// Tile: 128x64 interior, 136x72 loaded (right/bottom halo 8). 39.2 KB LDS -> 4 blocks/CU.
__global__ __launch_bounds__(256) void k_grad(const float* __restrict__ pred, const float* __restrict__ tgt,
                                              const float* __restrict__ shiftA, const float* __restrict__ sclA,
                                              float* __restrict__ gsum, uint32_t* __restrict__ gcnt) {
    __shared__ float d_lds[GLH * GLW];
    const int b = blockIdx.y;
    const int bx = blockIdx.x & 3;       // 4 tiles across (4*128 = 512)
    const int by = blockIdx.x >> 2;      // 8 tiles down  (8*64  = 512)
    const int x0 = bx * GTW, y0 = by * GTH;
    const int tid = threadIdx.x;
    const float sp = shiftA[b], st = shiftA[NBATCH+b];
    const float ivp = 1.f/sclA[b], ivt = 1.f/sclA[NBATCH+b];
    const float NANF = __int_as_float(0x7FC00000);

    const float4* p4 = (const float4*)pred;
    const float4* t4 = (const float4*)tgt;
    const size_t base4 = (size_t)b * (NPIX/4);

    // ---- load 136x72 tile of both tensors, compute d, stage to LDS ----
    for (int i = tid; i < GLH * GL4; i += 256) {
        const int r = i / GL4, c4 = i - r * GL4;
        int yg = y0 + r;  if (yg > HH-1) yg = HH-1;                 // clamp (never read back)
        int c4g = (x0 >> 2) + c4;
        if (c4g > (WW >> 2) - 1) c4g = (WW >> 2) - 1;               // clamp (never read back)
        const size_t gidx = base4 + (size_t)yg * (WW/4) + c4g;
        const float4 pv = p4[gidx], tv = t4[gidx];
        float dd[4];
        dd[0] = (tv.x > st) ? (pv.x - sp)*ivp - (tv.x - st)*ivt : NANF;
        dd[1] = (tv.y > st) ? (pv.y - sp)*ivp - (tv.y - st)*ivt : NANF;
        dd[2] = (tv.z > st) ? (pv.z - sp)*ivp - (tv.z - st)*ivt : NANF;
        dd[3] = (tv.w > st) ? (pv.w - sp)*ivp - (tv.w - st)*ivt : NANF;
        *(float4*)&d_lds[r * GLW + c4 * 4] = *(float4*)dd;
    }
    __syncthreads();

    // ---- compute: thread owns column x_local = tid%128, rows y_base, y_base+2, ... ----
    const int xl = tid & (GTW - 1);
    const int yb = tid >> 7;             // 0 or 1
    const int xg = x0 + xl;
    float gs[4] = {0.f,0.f,0.f,0.f};
    uint32_t gc[4] = {0u,0u,0u,0u};
#pragma unroll 4
    for (int k = 0; k < GTH/2; ++k) {
        const int yl = yb + 2*k;
        const int yg = y0 + yl;
        const float d0 = d_lds[yl * GLW + xl];
        const bool m0 = (d0 == d0);
#pragma unroll
        for (int sL = 0; sL < 4; ++sL) {
            const int s = 1 << sL;
            if ((xl & (s-1)) || (yl & (s-1))) continue;
            if (m0) gc[sL] += 1u;
            if (xg + s < WW) {
                const float v = fabsf(d_lds[yl * GLW + xl + s] - d0);
                if (v == v) gs[sL] += v;
            }
            if (yg + s < HH) {
                const float v = fabsf(d_lds[(yl + s) * GLW + xl] - d0);
                if (v == v) gs[sL] += v;
            }
        }
    }

    // ---- block reduce + global atomics ----
    __shared__ float ls[4][4];
    __shared__ uint32_t lc[4][4];
    const int lane = tid & 63, wv = tid >> 6;
#pragma unroll
    for (int sL = 0; sL < 4; ++sL) {
        float v = gs[sL]; uint32_t cc = gc[sL];
        for (int off = 32; off; off >>= 1) { v += __shfl_down(v, off, 64); cc += __shfl_down(cc, off, 64); }
        if (lane == 0) { ls[sL][wv] = v; lc[sL][wv] = cc; }
    }
    __syncthreads();
    if (tid < 4) {
        const int sL = tid;
        float v = ls[sL][0] + ls[sL][1] + ls[sL][2] + ls[sL][3];
        uint32_t cc = lc[sL][0] + lc[sL][1] + lc[sL][2] + lc[sL][3];
        if (v != 0.f) atomicAdd(&gsum[sL*NBATCH + b], v);
        if (cc)       atomicAdd(&gcnt[sL*NBATCH + b], cc);
    }
}

// ================= final combine =================
__global__ void k_final(const float* __restrict__ trima, const float* __restrict__ gsum,
                        const uint32_t* __restrict__ gcnt, float* __restrict__ out) {
    const int b = threadIdx.x;  // 64 threads, one wave
    float v = trima[b];
#pragma unroll
    for (int sL = 0; sL < 4; ++sL) {
        uint32_t cc = gcnt[sL*NBATCH + b];
        float g = cc ? gsum[sL*NBATCH + b] / (float)cc : 0.f;
        v += 0.5f * g;   // ALPHA = 0.5
    }
    for (int off = 32; off; off >>= 1) v += __shfl_down(v, off, 64);
    if (b == 0) out[0] = v * (1.f/64.f);
}

extern "C" void kernel_launch(void* const* d_in, const int* in_sizes, int n_in,
                              void* d_out, int out_size, void* d_ws, size_t ws_size,
                              hipStream_t stream) {
    const float* pred = (const float*)d_in[0];
    const float* tgt  = (const float*)d_in[1];
    uint32_t* wu = (uint32_t*)d_ws;
    float*    wf = (float*)d_ws;
    if (ws_size < (size_t)WS_TOTAL * 4) return;  // ~5.26 MB needed

    hipMemsetAsync(d_ws, 0, (size_t)WS_TOTAL * 4, stream);
    dim3 hg(HGX, NBATCH);

    // --- medians + robust scales for pred & tgt (3-level radix select, sum-augmented) ---
    k_medhist1<<<hg, 256, 0, stream>>>(pred, tgt, wu + OFF_C1, wf + OFF_S1);
    k_select<<<128, 256, 0, stream>>>(wu, wf, wu + OFF_C1, wf + OFF_S1, BINS1, 0, 0);
    k_medhist2<<<hg, 256, 0, stream>>>(pred, tgt, wu + ST_B1, wu + OFF_C2, wf + OFF_S2);
    k_select<<<128, 256, 0, stream>>>(wu, wf, wu + OFF_C2, wf + OFF_S2, BINS2, 1, 0);
    k_medhist3<<<hg, 256, 0, stream>>>(pred, tgt, wu + ST_B1, wu + ST_B2, wu + OFF_C3, wf + OFF_S3);
    k_select<<<128, 256, 0, stream>>>(wu, wf, wu + OFF_C3, wf + OFF_S3, BINS3, 2, 0);

    // --- trimmed MAE: rank-select over residuals + prefix sum (re-zero hist region only) ---
    hipMemsetAsync(d_ws, 0, (size_t)OFF_STATE * 4, stream);
    k_reshist1<<<hg, 256, 0, stream>>>(pred, tgt, wf + ST_SHIFT, wf + ST_SCL, wu + OFF_C1, wf + OFF_S1);
    k_select<<<64, 256, 0, stream>>>(wu, wf, wu + OFF_C1, wf + OFF_S1, BINS1, 0, 1);
    k_reshist2<<<hg, 256, 0, stream>>>(pred, tgt, wf + ST_SHIFT, wf + ST_SCL, wu + ST_B1, wu + OFF_C2, wf + OFF_S2);
    k_select<<<64, 256, 0, stream>>>(wu, wf, wu + OFF_C2, wf + OFF_S2, BINS2, 1, 1);
    k_reshist3<<<hg, 256, 0, stream>>>(pred, tgt, wf + ST_SHIFT, wf + ST_SCL, wu + ST_B1, wu + ST_B2, wu + OFF_C3, wf + OFF_S3);
    k_select<<<64, 256, 0, stream>>>(wu, wf, wu + OFF_C3, wf + OFF_S3, BINS3, 2, 1);

    // --- fused multiscale gradient loss (tiled) ---
    k_grad<<<dim3(32, NBATCH), 256, 0, stream>>>(pred, tgt, wf + ST_SHIFT, wf + ST_SCL,
                                                 wf + ST_GSUM, wu + ST_GCNT);
    // --- combine ---
    k_final<<<1, 64, 0, stream>>>(wf + ST_TRIMA, wf + ST_GSUM, wu + ST_GCNT, (float*)d_out);
}

// Round 4
// 265.404 us; speedup vs baseline: 4.0209x; 1.9125x over previous
//
#include <hip/hip_runtime.h>
#include <stdint.h>

#define NBATCH 64
#define HH 512
#define WW 512
#define NPIX 262144            // 512*512
#define BINS1 2048             // key bits [31:21]
#define BINS2 2048             // key bits [20:10]
#define BINS3 1024             // key bits [9:0]
#define TRIM_IDX 209715u       // int((1-0.2)*262144)
#define HGX 32                 // hist blocks per batch
#define HITER (NPIX/4/HGX/256) // float4 iters per hist block (= 8)

// ---------------- workspace layout (u32 units), counts-only ----------------
#define SZ_C1 (2*NBATCH*BINS1)
#define OFF_C1 0
#define OFF_C2 (OFF_C1 + SZ_C1)
#define SZ_C3 (2*NBATCH*BINS3)
#define OFF_C3 (OFF_C2 + SZ_C1)
#define OFF_STATE (OFF_C3 + SZ_C3)
// state (survives the mid-pipeline hist re-zero):
#define ST_N     (OFF_STATE)        // u32 [128]  masked count per (tensor,batch)
#define ST_N2    (ST_N + 128)       // u32 [128]  #{x > median} (trim/grad mask count)
#define ST_B1    (ST_N2 + 128)      // u32 [128]
#define ST_B2    (ST_B1 + 128)      // u32 [128]
#define ST_RANK  (ST_B2 + 128)      // u32 [128]
#define ST_CLT   (ST_RANK + 128)    // u32 [128]  count of keys strictly below bucket
#define ST_SHIFT (ST_CLT + 128)     // f32 [128]  median per (tensor,batch)
#define ST_SCL   (ST_SHIFT + 128)   // f32 [128]  robust scale
#define ST_MAD   (ST_SCL + 128)     // f32 [128]  sum |x - median| (masked)
#define ST_THR   (ST_MAD + 128)     // f32 [64]   trim threshold per batch
#define ST_TSUM  (ST_THR + 64)      // f32 [64]   sum of residuals <= thr
#define ST_GSUM  (ST_TSUM + 64)     // f32 [4*64] gradient sums
#define ST_GCNT  (ST_GSUM + 256)    // u32 [4*64] gradient mask counts
#define WS_TOTAL (ST_GCNT + 256)

// gradient tile geometry
#define GTW 128                // interior tile width
#define GTH 64                 // interior tile height
#define GHALO 8
#define GLW (GTW + GHALO)      // 136 loaded cols
#define GLH (GTH + GHALO)      // 72 loaded rows
#define GL4 (GLW/4)            // 34 float4 per row

// order-preserving float -> u32 key (total order incl. negatives)
__device__ __forceinline__ uint32_t fkey(float x) {
    uint32_t u = __float_as_uint(x);
    return (u & 0x80000000u) ? ~u : (u | 0x80000000u);
}
__device__ __forceinline__ float funkey(uint32_t k) {
    return __uint_as_float((k & 0x80000000u) ? (k & 0x7fffffffu) : ~k);
}
// shared normalized-diff expression: MUST be the single source of truth so the
// trim threshold (from k_reshist*) and the trim sum (in k_grad) tie bit-exactly.
__device__ __forceinline__ float norm_diff(float p, float t, float sp, float ivp, float st, float ivt) {
    return (p - sp)*ivp - (t - st)*ivt;
}

// ================= median histogram passes (counts only, mask = tgt>0) ===========
__global__ __launch_bounds__(256) void k_medhist1(const float* __restrict__ pred, const float* __restrict__ tgt,
                                                  uint32_t* __restrict__ cnt) {
    __shared__ uint32_t cP[BINS1], cT[BINS1];
    const int tid = threadIdx.x;
    for (int i = tid; i < BINS1; i += 256) { cP[i]=0u; cT[i]=0u; }
    __syncthreads();
    const int b = blockIdx.y;
    const float4* p4 = (const float4*)pred;
    const float4* t4 = (const float4*)tgt;
    size_t base = (size_t)b*(NPIX/4) + (size_t)blockIdx.x*(NPIX/4/HGX);
    for (int it = 0; it < HITER; ++it) {
        size_t idx = base + (size_t)it*256 + tid;
        float4 pv = p4[idx], tv = t4[idx];
        float pa[4] = {pv.x, pv.y, pv.z, pv.w};
        float ta[4] = {tv.x, tv.y, tv.z, tv.w};
#pragma unroll
        for (int j = 0; j < 4; ++j) {
            if (ta[j] > 0.f) {
                atomicAdd(&cP[fkey(pa[j]) >> 21], 1u);
                atomicAdd(&cT[fkey(ta[j]) >> 21], 1u);
            }
        }
    }
    __syncthreads();
    for (int i = tid; i < BINS1; i += 256) {
        if (cP[i]) atomicAdd(&cnt[(size_t)b*BINS1+i], cP[i]);
        if (cT[i]) atomicAdd(&cnt[(size_t)(NBATCH+b)*BINS1+i], cT[i]);
    }
}

__global__ __launch_bounds__(256) void k_medhist2(const float* __restrict__ pred, const float* __restrict__ tgt,
                                                  const uint32_t* __restrict__ b1arr,
                                                  uint32_t* __restrict__ cnt) {
    __shared__ uint32_t cP[BINS2], cT[BINS2];
    const int tid = threadIdx.x;
    for (int i = tid; i < BINS2; i += 256) { cP[i]=0u; cT[i]=0u; }
    __syncthreads();
    const int b = blockIdx.y;
    const uint32_t b1p = b1arr[b], b1t = b1arr[NBATCH+b];
    const float4* p4 = (const float4*)pred;
    const float4* t4 = (const float4*)tgt;
    size_t base = (size_t)b*(NPIX/4) + (size_t)blockIdx.x*(NPIX/4/HGX);
    for (int it = 0; it < HITER; ++it) {
        size_t idx = base + (size_t)it*256 + tid;
        float4 pv = p4[idx], tv = t4[idx];
        float pa[4] = {pv.x, pv.y, pv.z, pv.w};
        float ta[4] = {tv.x, tv.y, tv.z, tv.w};
#pragma unroll
        for (int j = 0; j < 4; ++j) {
            if (ta[j] > 0.f) {
                uint32_t kp = fkey(pa[j]), kt = fkey(ta[j]);
                if ((kp >> 21) == b1p) atomicAdd(&cP[(kp>>10)&2047u], 1u);
                if ((kt >> 21) == b1t) atomicAdd(&cT[(kt>>10)&2047u], 1u);
            }
        }
    }
    __syncthreads();
    for (int i = tid; i < BINS2; i += 256) {
        if (cP[i]) atomicAdd(&cnt[(size_t)b*BINS2+i], cP[i]);
        if (cT[i]) atomicAdd(&cnt[(size_t)(NBATCH+b)*BINS2+i], cT[i]);
    }
}

__global__ __launch_bounds__(256) void k_medhist3(const float* __restrict__ pred, const float* __restrict__ tgt,
                                                  const uint32_t* __restrict__ b1arr, const uint32_t* __restrict__ b2arr,
                                                  uint32_t* __restrict__ cnt) {
    __shared__ uint32_t cP[BINS3], cT[BINS3];
    const int tid = threadIdx.x;
    for (int i = tid; i < BINS3; i += 256) { cP[i]=0u; cT[i]=0u; }
    __syncthreads();
    const int b = blockIdx.y;
    const uint32_t t22p = (b1arr[b]<<11) | b2arr[b];
    const uint32_t t22t = (b1arr[NBATCH+b]<<11) | b2arr[NBATCH+b];
    const float4* p4 = (const float4*)pred;
    const float4* t4 = (const float4*)tgt;
    size_t base = (size_t)b*(NPIX/4) + (size_t)blockIdx.x*(NPIX/4/HGX);
    for (int it = 0; it < HITER; ++it) {
        size_t idx = base + (size_t)it*256 + tid;
        float4 pv = p4[idx], tv = t4[idx];
        float pa[4] = {pv.x, pv.y, pv.z, pv.w};
        float ta[4] = {tv.x, tv.y, tv.z, tv.w};
#pragma unroll
        for (int j = 0; j < 4; ++j) {
            if (ta[j] > 0.f) {
                uint32_t kp = fkey(pa[j]), kt = fkey(ta[j]);
                if ((kp >> 10) == t22p) atomicAdd(&cP[kp&1023u], 1u);
                if ((kt >> 10) == t22t) atomicAdd(&cT[kt&1023u], 1u);
            }
        }
    }
    __syncthreads();
    for (int i = tid; i < BINS3; i += 256) {
        if (cP[i]) atomicAdd(&cnt[(size_t)b*BINS3+i], cP[i]);
        if (cT[i]) atomicAdd(&cnt[(size_t)(NBATCH+b)*BINS3+i], cT[i]);
    }
}

// ===== streaming MAD pass: sum |x - median| over the ORIGINAL mask (t>0), both tensors =====
__global__ __launch_bounds__(256) void k_mad(const float* __restrict__ pred, const float* __restrict__ tgt,
                                             const float* __restrict__ shiftA, float* __restrict__ madA) {
    const int b = blockIdx.y;
    const int tid = threadIdx.x;
    const float mp = shiftA[b], mt = shiftA[NBATCH+b];
    const float4* p4 = (const float4*)pred;
    const float4* t4 = (const float4*)tgt;
    size_t base = (size_t)b*(NPIX/4) + (size_t)blockIdx.x*(NPIX/4/HGX);
    float aP = 0.f, aT = 0.f;
    for (int it = 0; it < HITER; ++it) {
        size_t idx = base + (size_t)it*256 + tid;
        float4 pv = p4[idx], tv = t4[idx];
        float pa[4] = {pv.x, pv.y, pv.z, pv.w};
        float ta[4] = {tv.x, tv.y, tv.z, tv.w};
#pragma unroll
        for (int j = 0; j < 4; ++j) {
            if (ta[j] > 0.f) { aP += fabsf(pa[j] - mp); aT += fabsf(ta[j] - mt); }
        }
    }
    __shared__ float lsP[4], lsT[4];
    const int lane = tid & 63, wv = tid >> 6;
    for (int off = 32; off; off >>= 1) { aP += __shfl_down(aP, off, 64); aT += __shfl_down(aT, off, 64); }
    if (lane == 0) { lsP[wv] = aP; lsT[wv] = aT; }
    __syncthreads();
    if (tid == 0) atomicAdd(&madA[b],         lsP[0]+lsP[1]+lsP[2]+lsP[3]);
    if (tid == 1) atomicAdd(&madA[NBATCH+b],  lsT[0]+lsT[1]+lsT[2]+lsT[3]);
}

// tiny: scale = mad/n, 0 -> 1
__global__ void k_scale(const uint32_t* __restrict__ wu, float* __restrict__ wf) {
    const int q = threadIdx.x;  // 128
    uint32_t n = wu[ST_N + q];
    float sc = wf[ST_MAD + q] / (float)(n ? n : 1u);
    if (sc == 0.f) sc = 1.f;
    wf[ST_SCL + q] = sc;
}

// ===== residual passes. Mask is the NORMALIZED-target mask: t_n > 0 <=> t > median_t.
// v = mask ? |p_n - t_n| : 0, over ALL N elements (zeros participate in the rank).
__global__ __launch_bounds__(256) void k_reshist1(const float* __restrict__ pred, const float* __restrict__ tgt,
                                                  const float* __restrict__ shiftA, const float* __restrict__ sclA,
                                                  uint32_t* __restrict__ cnt) {
    __shared__ uint32_t cR[BINS1];
    const int tid = threadIdx.x;
    for (int i = tid; i < BINS1; i += 256) cR[i]=0u;
    __syncthreads();
    const int b = blockIdx.y;
    const float sp = shiftA[b], st = shiftA[NBATCH+b];
    const float ivp = 1.f/sclA[b], ivt = 1.f/sclA[NBATCH+b];
    const float4* p4 = (const float4*)pred;
    const float4* t4 = (const float4*)tgt;
    size_t base = (size_t)b*(NPIX/4) + (size_t)blockIdx.x*(NPIX/4/HGX);
    uint32_t zc = 0;   // masked-out elements -> v = 0.0 -> bin 1024; count in register
    for (int it = 0; it < HITER; ++it) {
        size_t idx = base + (size_t)it*256 + tid;
        float4 pv = p4[idx], tv = t4[idx];
        float pa[4] = {pv.x, pv.y, pv.z, pv.w};
        float ta[4] = {tv.x, tv.y, tv.z, tv.w};
#pragma unroll
        for (int j = 0; j < 4; ++j) {
            if (ta[j] > st) {
                float v = fabsf(norm_diff(pa[j], ta[j], sp, ivp, st, ivt));
                atomicAdd(&cR[fkey(v) >> 21], 1u);
            } else ++zc;
        }
    }
    for (int off = 32; off; off >>= 1) zc += __shfl_down(zc, off, 64);
    if ((tid & 63) == 0 && zc) atomicAdd(&cR[1024], zc);   // fkey(0.f)>>21 == 1024
    __syncthreads();
    for (int i = tid; i < BINS1; i += 256) {
        if (cR[i]) atomicAdd(&cnt[(size_t)b*BINS1+i], cR[i]);
    }
}

__global__ __launch_bounds__(256) void k_reshist2(const float* __restrict__ pred, const float* __restrict__ tgt,
                                                  const float* __restrict__ shiftA, const float* __restrict__ sclA,
                                                  const uint32_t* __restrict__ b1arr,
                                                  uint32_t* __restrict__ cnt) {
    __shared__ uint32_t cR[BINS2];
    const int tid = threadIdx.x;
    for (int i = tid; i < BINS2; i += 256) cR[i]=0u;
    __syncthreads();
    const int b = blockIdx.y;
    const float sp = shiftA[b], st = shiftA[NBATCH+b];
    const float ivp = 1.f/sclA[b], ivt = 1.f/sclA[NBATCH+b];
    const uint32_t rb1 = b1arr[b];
    const float4* p4 = (const float4*)pred;
    const float4* t4 = (const float4*)tgt;
    size_t base = (size_t)b*(NPIX/4) + (size_t)blockIdx.x*(NPIX/4/HGX);
    for (int it = 0; it < HITER; ++it) {
        size_t idx = base + (size_t)it*256 + tid;
        float4 pv = p4[idx], tv = t4[idx];
        float pa[4] = {pv.x, pv.y, pv.z, pv.w};
        float ta[4] = {tv.x, tv.y, tv.z, tv.w};
#pragma unroll
        for (int j = 0; j < 4; ++j) {
            float v = (ta[j] > st) ? fabsf(norm_diff(pa[j], ta[j], sp, ivp, st, ivt)) : 0.f;
            uint32_t k = fkey(v);
            if ((k >> 21) == rb1) atomicAdd(&cR[(k>>10)&2047u], 1u);
        }
    }
    __syncthreads();
    for (int i = tid; i < BINS2; i += 256) {
        if (cR[i]) atomicAdd(&cnt[(size_t)b*BINS2+i], cR[i]);
    }
}

__global__ __launch_bounds__(256) void k_reshist3(const float* __restrict__ pred, const float* __restrict__ tgt,
                                                  const float* __restrict__ shiftA, const float* __restrict__ sclA,
                                                  const uint32_t* __restrict__ b1arr, const uint32_t* __restrict__ b2arr,
                                                  uint32_t* __restrict__ cnt) {
    __shared__ uint32_t cR[BINS3];
    const int tid = threadIdx.x;
    for (int i = tid; i < BINS3; i += 256) cR[i]=0u;
    __syncthreads();
    const int b = blockIdx.y;
    const float sp = shiftA[b], st = shiftA[NBATCH+b];
    const float ivp = 1.f/sclA[b], ivt = 1.f/sclA[NBATCH+b];
    const uint32_t t22 = (b1arr[b]<<11) | b2arr[b];
    const float4* p4 = (const float4*)pred;
    const float4* t4 = (const float4*)tgt;
    size_t base = (size_t)b*(NPIX/4) + (size_t)blockIdx.x*(NPIX/4/HGX);
    for (int it = 0; it < HITER; ++it) {
        size_t idx = base + (size_t)it*256 + tid;
        float4 pv = p4[idx], tv = t4[idx];
        float pa[4] = {pv.x, pv.y, pv.z, pv.w};
        float ta[4] = {tv.x, tv.y, tv.z, tv.w};
#pragma unroll
        for (int j = 0; j < 4; ++j) {
            float v = (ta[j] > st) ? fabsf(norm_diff(pa[j], ta[j], sp, ivp, st, ivt)) : 0.f;
            uint32_t k = fkey(v);
            if ((k >> 10) == t22) atomicAdd(&cR[k&1023u], 1u);
        }
    }
    __syncthreads();
    for (int i = tid; i < BINS3; i += 256) {
        if (cR[i]) atomicAdd(&cnt[(size_t)b*BINS3+i], cR[i]);
    }
}

// ================= generic level select (counts only) =================
// mode 0 = median (q in [0,128)), mode 1 = residual (q in [0,64))
__global__ __launch_bounds__(256) void k_select(uint32_t* wu, float* wf,
                                                const uint32_t* cnt,
                                                int nbins, int level, int mode) {
    const int q = blockIdx.x;
    const int tid = threadIdx.x;
    const int bpt = nbins >> 8;
    const uint32_t* c = cnt + (size_t)q*nbins + (size_t)tid*bpt;
    uint32_t tcnt = 0;
    for (int j = 0; j < bpt; ++j) tcnt += c[j];
    __shared__ uint32_t sc[256];
    sc[tid] = tcnt;
    __syncthreads();
    for (int off = 1; off < 256; off <<= 1) {
        uint32_t u = 0;
        if (tid >= off) u = sc[tid-off];
        __syncthreads();
        if (tid >= off) sc[tid] += u;
        __syncthreads();
    }
    const uint32_t total = sc[255];
    const uint32_t excl = sc[tid] - tcnt;

    uint32_t r;
    if (level == 0) {
        if (mode == 0) {
            if (tid == 0) wu[ST_N+q] = total;
            r = total ? (total - 1u) / 2u : 0u;   // lower median rank
        } else {
            uint32_t n2 = wu[ST_N2 + NBATCH + q]; // #{t > median_t} = trim/grad mask count
            uint32_t mi = (uint32_t)NPIX - n2 + TRIM_IDX;
            if (mi > (uint32_t)NPIX - 1u) mi = (uint32_t)NPIX - 1u;
            r = mi;
        }
    } else {
        r = wu[ST_RANK+q];
    }
    __syncthreads();  // all threads read ST_RANK before the owner overwrites it

    if (total > 0u && excl <= r && r < excl + tcnt) {
        uint32_t cum = excl;
        for (int j = 0; j < bpt; ++j) {
            uint32_t cj = c[j];
            if (r < cum + cj) {
                uint32_t bidx = (uint32_t)(tid*bpt + j);
                if (level == 0) {
                    wu[ST_B1+q] = bidx; wu[ST_RANK+q] = r - cum; wu[ST_CLT+q] = cum;
                } else if (level == 1) {
                    wu[ST_B2+q] = bidx; wu[ST_RANK+q] = r - cum; wu[ST_CLT+q] += cum;
                } else {
                    uint32_t key = (wu[ST_B1+q] << 21) | (wu[ST_B2+q] << 10) | bidx;
                    float val = funkey(key);                   // exact selected value
                    if (mode == 0) {
                        uint32_t n = wu[ST_N+q];
                        uint32_t c_le = wu[ST_CLT+q] + cum + cj;  // count of x <= median (masked)
                        wf[ST_SHIFT+q] = val;
                        wu[ST_N2+q] = n - c_le;                   // #{x > median}
                    } else {
                        wf[ST_THR+q] = val;                       // exact trim threshold
                    }
                }
                break;
            }
            cum += cj;
        }
    }
    if (tid == 0 && total == 0u) {  // degenerate guard
        if (level == 0)      { wu[ST_B1+q]=0; wu[ST_RANK+q]=0; wu[ST_CLT+q]=0; }
        else if (level == 1) { wu[ST_B2+q]=0; }
        else {
            if (mode == 0) { wf[ST_SHIFT+q]=0.f; wu[ST_N2+q]=0u; }
            else           { wf[ST_THR+q]=0.f; }
        }
    }
}

// ===== fused 4-scale gradient loss + trimmed-MAE sum, LDS-tiled =====
// d = (p-sp)*ivp - (t-st)*ivt staged in LDS; NaN marks unmasked (t <= median_t).
// Tile: 128x64 interior, 136x72 loaded (right/bottom halo 8). 39.2 KB LDS.
__global__ __launch_bounds__(256) void k_grad(const float* __restrict__ pred, const float* __restrict__ tgt,
                                              const float* __restrict__ shiftA, const float* __restrict__ sclA,
                                              const float* __restrict__ thrA,
                                              float* __restrict__ gsum, uint32_t* __restrict__ gcnt,
                                              float* __restrict__ tsum) {
    __shared__ float d_lds[GLH * GLW];
    const int b = blockIdx.y;
    const int bx = blockIdx.x & 3;       // 4 tiles across (4*128 = 512)
    const int by = blockIdx.x >> 2;      // 8 tiles down  (8*64  = 512)
    const int x0 = bx * GTW, y0 = by * GTH;
    const int tid = threadIdx.x;
    const float sp = shiftA[b], st = shiftA[NBATCH+b];
    const float ivp = 1.f/sclA[b], ivt = 1.f/sclA[NBATCH+b];
    const float thr = thrA[b];
    const float NANF = __int_as_float(0x7FC00000);

    const float4* p4 = (const float4*)pred;
    const float4* t4 = (const float4*)tgt;
    const size_t base4 = (size_t)b * (NPIX/4);

    // ---- load 136x72 tile of both tensors, compute d, stage to LDS ----
    for (int i = tid; i < GLH * GL4; i += 256) {
        const int r = i / GL4, c4 = i - r * GL4;
        int yg = y0 + r;  if (yg > HH-1) yg = HH-1;                 // clamp (never read back)
        int c4g = (x0 >> 2) + c4;
        if (c4g > (WW >> 2) - 1) c4g = (WW >> 2) - 1;               // clamp (never read back)
        const size_t gidx = base4 + (size_t)yg * (WW/4) + c4g;
        const float4 pv = p4[gidx], tv = t4[gidx];
        float dd[4];
        dd[0] = (tv.x > st) ? norm_diff(pv.x, tv.x, sp, ivp, st, ivt) : NANF;
        dd[1] = (tv.y > st) ? norm_diff(pv.y, tv.y, sp, ivp, st, ivt) : NANF;
        dd[2] = (tv.z > st) ? norm_diff(pv.z, tv.z, sp, ivp, st, ivt) : NANF;
        dd[3] = (tv.w > st) ? norm_diff(pv.w, tv.w, sp, ivp, st, ivt) : NANF;
        *(float4*)&d_lds[r * GLW + c4 * 4] = *(float4*)dd;
    }
    __syncthreads();

    // ---- compute: thread owns column x_local = tid%128, rows yb, yb+2, ... ----
    const int xl = tid & (GTW - 1);
    const int yb = tid >> 7;             // 0 or 1
    const int xg = x0 + xl;
    float gs[4] = {0.f,0.f,0.f,0.f};
    uint32_t gc[4] = {0u,0u,0u,0u};
    float ts = 0.f;                      // trimmed residual sum over owned pixels
#pragma unroll 4
    for (int k = 0; k < GTH/2; ++k) {
        const int yl = yb + 2*k;
        const int yg = y0 + yl;
        const float d0 = d_lds[yl * GLW + xl];
        const bool m0 = (d0 == d0);
        if (m0) {
            const float a = fabsf(d0);
            if (a <= thr) ts += a;       // ties at thr included (res > thr excluded in ref)
        }
#pragma unroll
        for (int sL = 0; sL < 4; ++sL) {
            const int s = 1 << sL;
            if ((xl & (s-1)) || (yl & (s-1))) continue;
            if (m0) gc[sL] += 1u;
            if (xg + s < WW) {
                const float v = fabsf(d_lds[yl * GLW + xl + s] - d0);
                if (v == v) gs[sL] += v;
            }
            if (yg + s < HH) {
                const float v = fabsf(d_lds[(yl + s) * GLW + xl] - d0);
                if (v == v) gs[sL] += v;
            }
        }
    }

    // ---- block reduce + global atomics ----
    __shared__ float ls[4][4];
    __shared__ uint32_t lc[4][4];
    __shared__ float lt[4];
    const int lane = tid & 63, wv = tid >> 6;
#pragma unroll
    for (int sL = 0; sL < 4; ++sL) {
        float v = gs[sL]; uint32_t cc = gc[sL];
        for (int off = 32; off; off >>= 1) { v += __shfl_down(v, off, 64); cc += __shfl_down(cc, off, 64); }
        if (lane == 0) { ls[sL][wv] = v; lc[sL][wv] = cc; }
    }
    for (int off = 32; off; off >>= 1) ts += __shfl_down(ts, off, 64);
    if (lane == 0) lt[wv] = ts;
    __syncthreads();
    if (tid < 4) {
        const int sL = tid;
        float v = ls[sL][0] + ls[sL][1] + ls[sL][2] + ls[sL][3];
        uint32_t cc = lc[sL][0] + lc[sL][1] + lc[sL][2] + lc[sL][3];
        if (v != 0.f) atomicAdd(&gsum[sL*NBATCH + b], v);
        if (cc)       atomicAdd(&gcnt[sL*NBATCH + b], cc);
    }
    if (tid == 4) {
        float v = lt[0] + lt[1] + lt[2] + lt[3];
        if (v != 0.f) atomicAdd(&tsum[b], v);
    }
}

// ================= final combine =================
__global__ void k_final(const uint32_t* __restrict__ wu, const float* __restrict__ tsum,
                        const float* __restrict__ gsum, const uint32_t* __restrict__ gcnt,
                        float* __restrict__ out) {
    const int b = threadIdx.x;  // 64 threads, one wave
    uint32_t n2 = wu[ST_N2 + NBATCH + b];
    float v = n2 ? tsum[b] / (float)(2u*n2) : 0.f;
#pragma unroll
    for (int sL = 0; sL < 4; ++sL) {
        uint32_t cc = gcnt[sL*NBATCH + b];
        float g = cc ? gsum[sL*NBATCH + b] / (float)cc : 0.f;
        v += 0.5f * g;   // ALPHA = 0.5
    }
    for (int off = 32; off; off >>= 1) v += __shfl_down(v, off, 64);
    if (b == 0) out[0] = v * (1.f/64.f);
}

extern "C" void kernel_launch(void* const* d_in, const int* in_sizes, int n_in,
                              void* d_out, int out_size, void* d_ws, size_t ws_size,
                              hipStream_t stream) {
    const float* pred = (const float*)d_in[0];
    const float* tgt  = (const float*)d_in[1];
    uint32_t* wu = (uint32_t*)d_ws;
    float*    wf = (float*)d_ws;
    if (ws_size < (size_t)WS_TOTAL * 4) return;  // ~2.63 MB needed

    hipMemsetAsync(d_ws, 0, (size_t)WS_TOTAL * 4, stream);
    dim3 hg(HGX, NBATCH);

    // --- medians (3-level radix select, counts only) ---
    k_medhist1<<<hg, 256, 0, stream>>>(pred, tgt, wu + OFF_C1);
    k_select<<<128, 256, 0, stream>>>(wu, wf, wu + OFF_C1, BINS1, 0, 0);
    k_medhist2<<<hg, 256, 0, stream>>>(pred, tgt, wu + ST_B1, wu + OFF_C2);
    k_select<<<128, 256, 0, stream>>>(wu, wf, wu + OFF_C2, BINS2, 1, 0);
    k_medhist3<<<hg, 256, 0, stream>>>(pred, tgt, wu + ST_B1, wu + ST_B2, wu + OFF_C3);
    k_select<<<128, 256, 0, stream>>>(wu, wf, wu + OFF_C3, BINS3, 2, 0);

    // --- robust scale: streaming MAD pass + tiny divide ---
    k_mad<<<hg, 256, 0, stream>>>(pred, tgt, wf + ST_SHIFT, wf + ST_MAD);
    k_scale<<<1, 128, 0, stream>>>(wu, wf);

    // --- trimmed MAE: rank-select over residuals (counts only; re-zero hist region) ---
    hipMemsetAsync(d_ws, 0, (size_t)OFF_STATE * 4, stream);
    k_reshist1<<<hg, 256, 0, stream>>>(pred, tgt, wf + ST_SHIFT, wf + ST_SCL, wu + OFF_C1);
    k_select<<<64, 256, 0, stream>>>(wu, wf, wu + OFF_C1, BINS1, 0, 1);
    k_reshist2<<<hg, 256, 0, stream>>>(pred, tgt, wf + ST_SHIFT, wf + ST_SCL, wu + ST_B1, wu + OFF_C2);
    k_select<<<64, 256, 0, stream>>>(wu, wf, wu + OFF_C2, BINS2, 1, 1);
    k_reshist3<<<hg, 256, 0, stream>>>(pred, tgt, wf + ST_SHIFT, wf + ST_SCL, wu + ST_B1, wu + ST_B2, wu + OFF_C3);
    k_select<<<64, 256, 0, stream>>>(wu, wf, wu + OFF_C3, BINS3, 2, 1);

    // --- fused multiscale gradient loss + trimmed sum (tiled) ---
    k_grad<<<dim3(32, NBATCH), 256, 0, stream>>>(pred, tgt, wf + ST_SHIFT, wf + ST_SCL, wf + ST_THR,
                                                 wf + ST_GSUM, wu + ST_GCNT, wf + ST_TSUM);
    // --- combine ---
    k_final<<<1, 64, 0, stream>>>(wu, wf + ST_TSUM, wf + ST_GSUM, wu + ST_GCNT, (float*)d_out);
}

// Round 5
// 202.937 us; speedup vs baseline: 5.2586x; 1.3078x over previous
//
#include <hip/hip_runtime.h>
#include <stdint.h>

#define NBATCH 64
#define HH 512
#define WW 512
#define NPIX 262144            // 512*512
#define BINS1 2048             // key bits [31:21]
#define BINS2 2048             // key bits [20:10]
#define BINS3 1024             // key bits [9:0]
#define HGX 32                 // hist blocks per batch
#define HITER (NPIX/4/HGX/256) // float4 iters per hist block (= 8)

// ---------------- workspace layout (u32 units) ----------------
#define SZ_C1 (2*NBATCH*BINS1)
#define OFF_C1 0
#define OFF_C2 (OFF_C1 + SZ_C1)
#define SZ_C3 (2*NBATCH*BINS3)
#define OFF_C3 (OFF_C2 + SZ_C1)
#define OFF_SUM3 (OFF_C3 + SZ_C3)      // f32 [2*64][1024] level-3 bin sums
#define OFF_STATE (OFF_SUM3 + SZ_C3)
#define ST_N     (OFF_STATE)        // u32 [128] masked count per (tensor,batch)
#define ST_N2    (ST_N + 128)       // u32 [128] #{x > median}
#define ST_B1    (ST_N2 + 128)      // u32 [128]
#define ST_B2    (ST_B1 + 128)      // u32 [128]
#define ST_RANK  (ST_B2 + 128)      // u32 [128]
#define ST_CLT   (ST_RANK + 128)    // u32 [128] count strictly below bucket
#define ST_SHIFT (ST_CLT + 128)     // f32 [128] median
#define ST_SCL   (ST_SHIFT + 128)   // f32 [128] robust scale
#define ST_STOT  (ST_SCL + 128)     // f32 [128] sum of masked x
#define ST_S1    (ST_STOT + 128)    // f32 [128] sum of masked x, level-1 bucket < b1
#define ST_S2    (ST_S1 + 128)      // f32 [128] sum of masked x, bucket==b1, mid < b2
#define ST_TSUM  (ST_S2 + 128)      // f32 [64]  sum of residuals (trim is a no-op; proof in notes)
#define ST_GSUM  (ST_TSUM + 64)     // f32 [4*64] gradient sums
#define ST_GCNT  (ST_GSUM + 256)    // u32 [4*64] gradient mask counts
#define WS_TOTAL (ST_GCNT + 256)

// gradient tile geometry: 128x32 interior, 136x40 loaded -> 21.75 KB LDS, 7 blocks/CU
#define GTW 128
#define GTH 32
#define GHALO 8
#define GLW (GTW + GHALO)      // 136
#define GLH (GTH + GHALO)      // 40
#define GL4 (GLW/4)            // 34

// order-preserving float -> u32 key
__device__ __forceinline__ uint32_t fkey(float x) {
    uint32_t u = __float_as_uint(x);
    return (u & 0x80000000u) ? ~u : (u | 0x80000000u);
}
__device__ __forceinline__ float funkey(uint32_t k) {
    return __uint_as_float((k & 0x80000000u) ? (k & 0x7fffffffu) : ~k);
}
__device__ __forceinline__ float norm_diff(float p, float t, float sp, float ivp, float st, float ivt) {
    return (p - sp)*ivp - (t - st)*ivt;
}

// ===== medhist1: level-1 counts (mask = tgt>0) + streaming S_tot for both tensors =====
__global__ __launch_bounds__(256) void k_medhist1(const float* __restrict__ pred, const float* __restrict__ tgt,
                                                  uint32_t* __restrict__ cnt, float* __restrict__ stot) {
    __shared__ uint32_t cP[BINS1], cT[BINS1];
    __shared__ float redP[4], redT[4];
    const int tid = threadIdx.x;
    for (int i = tid; i < BINS1; i += 256) { cP[i]=0u; cT[i]=0u; }
    __syncthreads();
    const int b = blockIdx.y;
    const float4* p4 = (const float4*)pred;
    const float4* t4 = (const float4*)tgt;
    size_t base = (size_t)b*(NPIX/4) + (size_t)blockIdx.x*(NPIX/4/HGX);
    float aP = 0.f, aT = 0.f;
    for (int it = 0; it < HITER; ++it) {
        size_t idx = base + (size_t)it*256 + tid;
        float4 pv = p4[idx], tv = t4[idx];
        float pa[4] = {pv.x, pv.y, pv.z, pv.w};
        float ta[4] = {tv.x, tv.y, tv.z, tv.w};
#pragma unroll
        for (int j = 0; j < 4; ++j) {
            if (ta[j] > 0.f) {
                atomicAdd(&cP[fkey(pa[j]) >> 21], 1u);
                atomicAdd(&cT[fkey(ta[j]) >> 21], 1u);
                aP += pa[j]; aT += ta[j];
            }
        }
    }
    const int lane = tid & 63, wv = tid >> 6;
    for (int off = 32; off; off >>= 1) { aP += __shfl_down(aP, off, 64); aT += __shfl_down(aT, off, 64); }
    if (lane == 0) { redP[wv] = aP; redT[wv] = aT; }
    __syncthreads();
    if (tid == 0) atomicAdd(&stot[b],        redP[0]+redP[1]+redP[2]+redP[3]);
    if (tid == 1) atomicAdd(&stot[NBATCH+b], redT[0]+redT[1]+redT[2]+redT[3]);
    for (int i = tid; i < BINS1; i += 256) {
        if (cP[i]) atomicAdd(&cnt[(size_t)b*BINS1+i], cP[i]);
        if (cT[i]) atomicAdd(&cnt[(size_t)(NBATCH+b)*BINS1+i], cT[i]);
    }
}

// ===== medhist2: level-2 counts + streaming S1 (sum of x in buckets < b1) =====
__global__ __launch_bounds__(256) void k_medhist2(const float* __restrict__ pred, const float* __restrict__ tgt,
                                                  const uint32_t* __restrict__ b1arr,
                                                  uint32_t* __restrict__ cnt, float* __restrict__ s1arr) {
    __shared__ uint32_t cP[BINS2], cT[BINS2];
    __shared__ float redP[4], redT[4];
    const int tid = threadIdx.x;
    for (int i = tid; i < BINS2; i += 256) { cP[i]=0u; cT[i]=0u; }
    __syncthreads();
    const int b = blockIdx.y;
    const uint32_t b1p = b1arr[b], b1t = b1arr[NBATCH+b];
    const float4* p4 = (const float4*)pred;
    const float4* t4 = (const float4*)tgt;
    size_t base = (size_t)b*(NPIX/4) + (size_t)blockIdx.x*(NPIX/4/HGX);
    float aP = 0.f, aT = 0.f;
    for (int it = 0; it < HITER; ++it) {
        size_t idx = base + (size_t)it*256 + tid;
        float4 pv = p4[idx], tv = t4[idx];
        float pa[4] = {pv.x, pv.y, pv.z, pv.w};
        float ta[4] = {tv.x, tv.y, tv.z, tv.w};
#pragma unroll
        for (int j = 0; j < 4; ++j) {
            if (ta[j] > 0.f) {
                uint32_t kp = fkey(pa[j]), kt = fkey(ta[j]);
                uint32_t hp = kp >> 21, ht = kt >> 21;
                if (hp == b1p) atomicAdd(&cP[(kp>>10)&2047u], 1u);
                else if (hp < b1p) aP += pa[j];
                if (ht == b1t) atomicAdd(&cT[(kt>>10)&2047u], 1u);
                else if (ht < b1t) aT += ta[j];
            }
        }
    }
    const int lane = tid & 63, wv = tid >> 6;
    for (int off = 32; off; off >>= 1) { aP += __shfl_down(aP, off, 64); aT += __shfl_down(aT, off, 64); }
    if (lane == 0) { redP[wv] = aP; redT[wv] = aT; }
    __syncthreads();
    if (tid == 0) atomicAdd(&s1arr[b],        redP[0]+redP[1]+redP[2]+redP[3]);
    if (tid == 1) atomicAdd(&s1arr[NBATCH+b], redT[0]+redT[1]+redT[2]+redT[3]);
    for (int i = tid; i < BINS2; i += 256) {
        if (cP[i]) atomicAdd(&cnt[(size_t)b*BINS2+i], cP[i]);
        if (cT[i]) atomicAdd(&cnt[(size_t)(NBATCH+b)*BINS2+i], cT[i]);
    }
}

// ===== medhist3: level-3 counts + SUMS (few elems -> cheap) + streaming S2 =====
__global__ __launch_bounds__(256) void k_medhist3(const float* __restrict__ pred, const float* __restrict__ tgt,
                                                  const uint32_t* __restrict__ b1arr, const uint32_t* __restrict__ b2arr,
                                                  uint32_t* __restrict__ cnt, float* __restrict__ sum3,
                                                  float* __restrict__ s2arr) {
    __shared__ uint32_t cP[BINS3], cT[BINS3];
    __shared__ float sSP[BINS3], sST[BINS3];
    __shared__ float redP[4], redT[4];
    const int tid = threadIdx.x;
    for (int i = tid; i < BINS3; i += 256) { cP[i]=0u; cT[i]=0u; sSP[i]=0.f; sST[i]=0.f; }
    __syncthreads();
    const int b = blockIdx.y;
    const uint32_t b1p = b1arr[b], b1t = b1arr[NBATCH+b];
    const uint32_t t22p = (b1p<<11) | b2arr[b];
    const uint32_t t22t = (b1t<<11) | b2arr[NBATCH+b];
    const float4* p4 = (const float4*)pred;
    const float4* t4 = (const float4*)tgt;
    size_t base = (size_t)b*(NPIX/4) + (size_t)blockIdx.x*(NPIX/4/HGX);
    float aP = 0.f, aT = 0.f;
    for (int it = 0; it < HITER; ++it) {
        size_t idx = base + (size_t)it*256 + tid;
        float4 pv = p4[idx], tv = t4[idx];
        float pa[4] = {pv.x, pv.y, pv.z, pv.w};
        float ta[4] = {tv.x, tv.y, tv.z, tv.w};
#pragma unroll
        for (int j = 0; j < 4; ++j) {
            if (ta[j] > 0.f) {
                uint32_t kp = fkey(pa[j]), kt = fkey(ta[j]);
                if ((kp >> 10) == t22p) { atomicAdd(&cP[kp&1023u], 1u); atomicAdd(&sSP[kp&1023u], pa[j]); }
                else if ((kp >> 21) == b1p && (kp >> 10) < t22p) aP += pa[j];
                if ((kt >> 10) == t22t) { atomicAdd(&cT[kt&1023u], 1u); atomicAdd(&sST[kt&1023u], ta[j]); }
                else if ((kt >> 21) == b1t && (kt >> 10) < t22t) aT += ta[j];
            }
        }
    }
    const int lane = tid & 63, wv = tid >> 6;
    for (int off = 32; off; off >>= 1) { aP += __shfl_down(aP, off, 64); aT += __shfl_down(aT, off, 64); }
    if (lane == 0) { redP[wv] = aP; redT[wv] = aT; }
    __syncthreads();
    if (tid == 0) atomicAdd(&s2arr[b],        redP[0]+redP[1]+redP[2]+redP[3]);
    if (tid == 1) atomicAdd(&s2arr[NBATCH+b], redT[0]+redT[1]+redT[2]+redT[3]);
    for (int i = tid; i < BINS3; i += 256) {
        if (cP[i]) { atomicAdd(&cnt[(size_t)b*BINS3+i], cP[i]); atomicAdd(&sum3[(size_t)b*BINS3+i], sSP[i]); }
        if (cT[i]) { atomicAdd(&cnt[(size_t)(NBATCH+b)*BINS3+i], cT[i]); atomicAdd(&sum3[(size_t)(NBATCH+b)*BINS3+i], sST[i]); }
    }
}

// ===== generic level select (median path only). At level 2 also computes MAD scale. =====
__global__ __launch_bounds__(256) void k_select(uint32_t* wu, float* wf,
                                                const uint32_t* cnt, const float* sum3,
                                                int nbins, int level) {
    const int q = blockIdx.x;       // 128 problems: tensor*64+batch
    const int tid = threadIdx.x;
    const int bpt = nbins >> 8;
    const uint32_t* c  = cnt  + (size_t)q*nbins + (size_t)tid*bpt;
    const float*    s3 = sum3 + (size_t)q*nbins + (size_t)tid*bpt;
    uint32_t tcnt = 0; float tfs = 0.f;
    for (int j = 0; j < bpt; ++j) tcnt += c[j];
    if (level == 2) for (int j = 0; j < bpt; ++j) tfs += s3[j];
    __shared__ uint32_t sc[256];
    __shared__ float ss[256];
    sc[tid] = tcnt; ss[tid] = tfs;
    __syncthreads();
    for (int off = 1; off < 256; off <<= 1) {
        uint32_t u = 0; float f = 0.f;
        if (tid >= off) { u = sc[tid-off]; f = ss[tid-off]; }
        __syncthreads();
        if (tid >= off) { sc[tid] += u; ss[tid] += f; }
        __syncthreads();
    }
    const uint32_t total = sc[255];
    const uint32_t excl = sc[tid] - tcnt;
    const float exclS = ss[tid] - tfs;

    uint32_t r;
    if (level == 0) {
        if (tid == 0) wu[ST_N+q] = total;
        r = total ? (total - 1u) / 2u : 0u;   // lower median rank
    } else {
        r = wu[ST_RANK+q];
    }
    __syncthreads();  // all threads read ST_RANK before the owner overwrites it

    if (total > 0u && excl <= r && r < excl + tcnt) {
        uint32_t cum = excl; float fs = exclS;
        for (int j = 0; j < bpt; ++j) {
            uint32_t cj = c[j];
            if (r < cum + cj) {
                uint32_t bidx = (uint32_t)(tid*bpt + j);
                if (level == 0) {
                    wu[ST_B1+q] = bidx; wu[ST_RANK+q] = r - cum; wu[ST_CLT+q] = cum;
                } else if (level == 1) {
                    wu[ST_B2+q] = bidx; wu[ST_RANK+q] = r - cum; wu[ST_CLT+q] += cum;
                } else {
                    uint32_t key = (wu[ST_B1+q] << 21) | (wu[ST_B2+q] << 10) | bidx;
                    float m = funkey(key);                     // exact lower median
                    uint32_t n = wu[ST_N+q];
                    uint32_t c_le = wu[ST_CLT+q] + cum + cj;   // #{x <= m} (all in bin b3 share key)
                    float S_le = wf[ST_S1+q] + wf[ST_S2+q] + fs + s3[j];
                    float madsum = (float)(2u*c_le - n) * m + wf[ST_STOT+q] - 2.f*S_le;
                    float scale = madsum / (float)(n ? n : 1u);
                    if (!(scale > 0.f)) scale = 1.f;           // ref: scale==0 -> 1
                    wf[ST_SHIFT+q] = m; wf[ST_SCL+q] = scale;
                    wu[ST_N2+q] = n - c_le;                    // #{x > median}
                }
                break;
            }
            cum += cj;
            if (level == 2) fs += s3[j];
        }
    }
    if (tid == 0 && total == 0u) {  // degenerate guard (no masked elements)
        if (level == 0)      { wu[ST_B1+q]=0; wu[ST_RANK+q]=0; wu[ST_CLT+q]=0; }
        else if (level == 1) { wu[ST_B2+q]=0; }
        else                 { wf[ST_SHIFT+q]=0.f; wf[ST_SCL+q]=1.f; wu[ST_N2+q]=0u; }
    }
}

// ===== fused 4-scale gradient loss + full residual sum (trim is a provable no-op) =====
// d staged in LDS; NaN marks unmasked (t <= median_t). 128x32 interior, 136x40 loaded.
__global__ __launch_bounds__(256) void k_grad(const float* __restrict__ pred, const float* __restrict__ tgt,
                                              const float* __restrict__ shiftA, const float* __restrict__ sclA,
                                              float* __restrict__ gsum, uint32_t* __restrict__ gcnt,
                                              float* __restrict__ tsum) {
    __shared__ float d_lds[GLH * GLW];
    const int b = blockIdx.y;
    const int bx = blockIdx.x & 3;       // 4 tiles across (4*128 = 512)
    const int by = blockIdx.x >> 2;      // 16 tiles down (16*32 = 512)
    const int x0 = bx * GTW, y0 = by * GTH;
    const int tid = threadIdx.x;
    const float sp = shiftA[b], st = shiftA[NBATCH+b];
    const float ivp = 1.f/sclA[b], ivt = 1.f/sclA[NBATCH+b];
    const float NANF = __int_as_float(0x7FC00000);

    const float4* p4 = (const float4*)pred;
    const float4* t4 = (const float4*)tgt;
    const size_t base4 = (size_t)b * (NPIX/4);

    // ---- load 136x40 tile (clamped halo never read back), compute d, stage to LDS ----
    for (int i = tid; i < GLH * GL4; i += 256) {
        const int r = i / GL4, c4 = i - r * GL4;
        int yg = y0 + r;  if (yg > HH-1) yg = HH-1;
        int c4g = (x0 >> 2) + c4;
        if (c4g > (WW >> 2) - 1) c4g = (WW >> 2) - 1;
        const size_t gidx = base4 + (size_t)yg * (WW/4) + c4g;
        const float4 pv = p4[gidx], tv = t4[gidx];
        float dd[4];
        dd[0] = (tv.x > st) ? norm_diff(pv.x, tv.x, sp, ivp, st, ivt) : NANF;
        dd[1] = (tv.y > st) ? norm_diff(pv.y, tv.y, sp, ivp, st, ivt) : NANF;
        dd[2] = (tv.z > st) ? norm_diff(pv.z, tv.z, sp, ivp, st, ivt) : NANF;
        dd[3] = (tv.w > st) ? norm_diff(pv.w, tv.w, sp, ivp, st, ivt) : NANF;
        *(float4*)&d_lds[r * GLW + c4 * 4] = *(float4*)dd;
    }
    __syncthreads();

    // ---- compute: thread owns column xl = tid%128, rows yb, yb+2, ... (16 px) ----
    const int xl = tid & (GTW - 1);
    const int yb = tid >> 7;             // 0 or 1
    const int xg = x0 + xl;
    float gs[4] = {0.f,0.f,0.f,0.f};
    uint32_t gc[4] = {0u,0u,0u,0u};
    float ts = 0.f;
#pragma unroll 4
    for (int k = 0; k < GTH/2; ++k) {
        const int yl = yb + 2*k;
        const int yg = y0 + yl;
        const float d0 = d_lds[yl * GLW + xl];
        const bool m0 = (d0 == d0);
        if (m0) ts += fabsf(d0);         // trimmed sum == full sum (thr always clamps to max)
#pragma unroll
        for (int sL = 0; sL < 4; ++sL) {
            const int s = 1 << sL;
            if ((xl & (s-1)) || (yl & (s-1))) continue;
            if (m0) gc[sL] += 1u;
            if (xg + s < WW) {
                const float v = fabsf(d_lds[yl * GLW + xl + s] - d0);
                if (v == v) gs[sL] += v;
            }
            if (yg + s < HH) {
                const float v = fabsf(d_lds[(yl + s) * GLW + xl] - d0);
                if (v == v) gs[sL] += v;
            }
        }
    }

    // ---- block reduce + global atomics ----
    __shared__ float ls[4][4];
    __shared__ uint32_t lc[4][4];
    __shared__ float lt[4];
    const int lane = tid & 63, wv = tid >> 6;
#pragma unroll
    for (int sL = 0; sL < 4; ++sL) {
        float v = gs[sL]; uint32_t cc = gc[sL];
        for (int off = 32; off; off >>= 1) { v += __shfl_down(v, off, 64); cc += __shfl_down(cc, off, 64); }
        if (lane == 0) { ls[sL][wv] = v; lc[sL][wv] = cc; }
    }
    for (int off = 32; off; off >>= 1) ts += __shfl_down(ts, off, 64);
    if (lane == 0) lt[wv] = ts;
    __syncthreads();
    if (tid < 4) {
        const int sL = tid;
        float v = ls[sL][0] + ls[sL][1] + ls[sL][2] + ls[sL][3];
        uint32_t cc = lc[sL][0] + lc[sL][1] + lc[sL][2] + lc[sL][3];
        if (v != 0.f) atomicAdd(&gsum[sL*NBATCH + b], v);
        if (cc)       atomicAdd(&gcnt[sL*NBATCH + b], cc);
    }
    if (tid == 4) {
        float v = lt[0] + lt[1] + lt[2] + lt[3];
        if (v != 0.f) atomicAdd(&tsum[b], v);
    }
}

// ================= final combine =================
__global__ void k_final(const uint32_t* __restrict__ wu, const float* __restrict__ tsum,
                        const float* __restrict__ gsum, const uint32_t* __restrict__ gcnt,
                        float* __restrict__ out) {
    const int b = threadIdx.x;  // 64 threads, one wave
    uint32_t n2 = wu[ST_N2 + NBATCH + b];
    float v = n2 ? tsum[b] / (float)(2u*n2) : 0.f;
#pragma unroll
    for (int sL = 0; sL < 4; ++sL) {
        uint32_t cc = gcnt[sL*NBATCH + b];
        float g = cc ? gsum[sL*NBATCH + b] / (float)cc : 0.f;
        v += 0.5f * g;   // ALPHA = 0.5
    }
    for (int off = 32; off; off >>= 1) v += __shfl_down(v, off, 64);
    if (b == 0) out[0] = v * (1.f/64.f);
}

extern "C" void kernel_launch(void* const* d_in, const int* in_sizes, int n_in,
                              void* d_out, int out_size, void* d_ws, size_t ws_size,
                              hipStream_t stream) {
    const float* pred = (const float*)d_in[0];
    const float* tgt  = (const float*)d_in[1];
    uint32_t* wu = (uint32_t*)d_ws;
    float*    wf = (float*)d_ws;
    if (ws_size < (size_t)WS_TOTAL * 4) return;  // ~3.2 MB needed

    hipMemsetAsync(d_ws, 0, (size_t)WS_TOTAL * 4, stream);
    dim3 hg(HGX, NBATCH);

    // --- medians + analytic MAD scale (3-level radix select, sum-augmented level 3) ---
    k_medhist1<<<hg, 256, 0, stream>>>(pred, tgt, wu + OFF_C1, wf + ST_STOT);
    k_select<<<128, 256, 0, stream>>>(wu, wf, wu + OFF_C1, wf + OFF_SUM3, BINS1, 0);
    k_medhist2<<<hg, 256, 0, stream>>>(pred, tgt, wu + ST_B1, wu + OFF_C2, wf + ST_S1);
    k_select<<<128, 256, 0, stream>>>(wu, wf, wu + OFF_C2, wf + OFF_SUM3, BINS2, 1);
    k_medhist3<<<hg, 256, 0, stream>>>(pred, tgt, wu + ST_B1, wu + ST_B2, wu + OFF_C3,
                                       wf + OFF_SUM3, wf + ST_S2);
    k_select<<<128, 256, 0, stream>>>(wu, wf, wu + OFF_C3, wf + OFF_SUM3, BINS3, 2);

    // --- fused multiscale gradient loss + residual sum (tiled) ---
    k_grad<<<dim3(64, NBATCH), 256, 0, stream>>>(pred, tgt, wf + ST_SHIFT, wf + ST_SCL,
                                                 wf + ST_GSUM, wu + ST_GCNT, wf + ST_TSUM);
    // --- combine ---
    k_final<<<1, 64, 0, stream>>>(wu, wf + ST_TSUM, wf + ST_GSUM, wu + ST_GCNT, (float*)d_out);
}